// Round 4
// baseline (844.952 us; speedup 1.0000x reference)
//
#include <hip/hip_runtime.h>
#include <hip/hip_bf16.h>

#define EPS 1e-5f
typedef __hip_bfloat16 bf16;
typedef __attribute__((ext_vector_type(8))) short  short8;
typedef __attribute__((ext_vector_type(4))) float  f32x4;

__device__ __forceinline__ float b2f(bf16 v) { return __bfloat162float(v); }
__device__ __forceinline__ float bs2f(short s) { bf16 b = *reinterpret_cast<bf16*>(&s); return b2f(b); }
__device__ __forceinline__ float ldv(const void* p, size_t i, bool bf) {
    return bf ? b2f(((const bf16*)p)[i]) : ((const float*)p)[i];
}
__device__ __forceinline__ void stv(void* p, size_t i, float v, bool bf) {
    if (bf) ((bf16*)p)[i] = __float2bfloat16(v);
    else    ((float*)p)[i] = v;
}
__device__ __forceinline__ short f2bs(float v) {
    bf16 b = __float2bfloat16(v);
    return *reinterpret_cast<short*>(&b);
}
__device__ __forceinline__ short8 ld16s(const short* p) { return *(const short8*)p; }

// raw prefetch state for one edge-tile row (per lane)
struct RawE {
    short8 x0, x1, x2, x3;   // xb[s], xb[d] halves
    short8 eA, eB;           // bf16 e rows
    float4 f0, f1, f2, f3;   // f32 e paths
    short8 u0, u1;           // ub rows
};

// ---------------- dtype detector ----------------
__global__ void detect_dtype(const unsigned short* __restrict__ xs, float* __restrict__ flag) {
    __shared__ int cnt;
    if (threadIdx.x == 0) cnt = 0;
    __syncthreads();
    unsigned short u = xs[threadIdx.x];
    int e = (u >> 7) & 0xFF;
    int sane = (u == 0 || (e >= 110 && e <= 140)) ? 1 : 0;
    atomicAdd(&cnt, sane);
    __syncthreads();
    if (threadIdx.x == 0) flag[0] = (cnt >= 230) ? 1.0f : 0.0f;
}

// ---------------- BatchNorm stats ----------------
template<int C>
__global__ __launch_bounds__(256) void bn_stats(const void* __restrict__ in, int R,
                                                float* __restrict__ stats, const float* __restrict__ flag) {
    bool isbf = flag[0] != 0.f;
    const int RG = 256 / C;
    int c = threadIdx.x % C, rg = threadIdx.x / C;
    float s = 0.f, s2 = 0.f;
    if (isbf) {
        const bf16* ip = (const bf16*)in;
        for (int r = blockIdx.x * RG + rg; r < R; r += gridDim.x * RG) {
            float v = b2f(ip[(size_t)r * C + c]); s += v; s2 += v * v;
        }
    } else {
        const float* ip = (const float*)in;
        for (int r = blockIdx.x * RG + rg; r < R; r += gridDim.x * RG) {
            float v = ip[(size_t)r * C + c]; s += v; s2 += v * v;
        }
    }
    __shared__ float sm[2][256];
    sm[0][threadIdx.x] = s; sm[1][threadIdx.x] = s2;
    __syncthreads();
    if (threadIdx.x < C) {
        float ts = 0.f, t2 = 0.f;
        for (int g = 0; g < RG; g++) { ts += sm[0][g * C + c]; t2 += sm[1][g * C + c]; }
        atomicAdd(&stats[c], ts);
        atomicAdd(&stats[C + c], t2);
    }
}

// ---------------- BN apply: x -> bf16 internal ----------------
__global__ __launch_bounds__(256) void bn_apply_x(const void* __restrict__ in, short* __restrict__ out,
                                                  const float* __restrict__ stats, int R,
                                                  const void* __restrict__ gamma, const void* __restrict__ beta,
                                                  const float* __restrict__ flag) {
    bool isbf = flag[0] != 0.f;
    int total = R * 64;
    for (int i = blockIdx.x * 256 + threadIdx.x; i < total; i += gridDim.x * 256) {
        int c = i & 63;
        float mean = stats[c] / (float)R;
        float var = stats[64 + c] / (float)R - mean * mean;
        float inv = rsqrtf(var + EPS);
        out[i] = f2bs(ldv(gamma, c, isbf) * (ldv(in, i, isbf) - mean) * inv + ldv(beta, c, isbf));
    }
}

// ---------------- BN apply: u -> f32 + bf16 tables ----------------
__global__ __launch_bounds__(256) void bn_apply_u(const void* __restrict__ in, float* __restrict__ outf,
                                                  short* __restrict__ outb,
                                                  const float* __restrict__ stats, int R,
                                                  const void* __restrict__ gamma, const void* __restrict__ beta,
                                                  const float* __restrict__ flag) {
    bool isbf = flag[0] != 0.f;
    int total = R * 32;
    for (int i = blockIdx.x * 256 + threadIdx.x; i < total; i += gridDim.x * 256) {
        int c = i & 31;
        float mean = stats[c] / (float)R;
        float var = stats[32 + c] / (float)R - mean * mean;
        float inv = rsqrtf(var + EPS);
        float v = ldv(gamma, c, isbf) * (ldv(in, i, isbf) - mean) * inv + ldv(beta, c, isbf);
        outf[i] = v; outb[i] = f2bs(v);
    }
}

// ---------------- per-dst edge counts ----------------
__global__ __launch_bounds__(256) void count_kernel(const int* __restrict__ ei, int* __restrict__ cnt, int E) {
    int stride = gridDim.x * 256;
    for (int t = blockIdx.x * 256 + threadIdx.x; t < E; t += stride) atomicAdd(&cnt[ei[E + t]], 1);
}

// ---------------- CSR offsets + per-graph ranges (merged) ----------------
__global__ __launch_bounds__(256) void csr_offsets(const int* __restrict__ cnt, int* __restrict__ off,
                                                   int* __restrict__ wcur, int* __restrict__ cursor, int N,
                                                   const int* __restrict__ batch, int* __restrict__ gstart, int B) {
    int n = blockIdx.x * 256 + threadIdx.x;
    if (n < N) {
        int o = atomicAdd(cursor, cnt[n]);
        off[n] = o; wcur[n] = o;
    }
    if (blockIdx.x == 0 && threadIdx.x <= B) {
        int t = threadIdx.x;
        int lo = 0, hi = N;
        while (lo < hi) { int mid = (lo + hi) >> 1; if (batch[mid] < t) lo = mid + 1; else hi = mid; }
        gstart[t] = lo;
    }
}

__global__ __launch_bounds__(256) void csr_fill(const int* __restrict__ ei, int* __restrict__ wcur,
                                                int* __restrict__ csr, int E) {
    int stride = gridDim.x * 256;
    for (int t = blockIdx.x * 256 + threadIdx.x; t < E; t += stride) {
        int d = ei[E + t];
        int pos = atomicAdd(&wcur[d], 1);
        csr[pos] = t;
    }
}

// ---------------- W transpose prep ----------------
__global__ __launch_bounds__(256) void transpose_w(
    const void* __restrict__ W0, const void* __restrict__ W1, const void* __restrict__ W2,
    const void* __restrict__ W3, const void* __restrict__ W4, const void* __restrict__ W5,
    short* __restrict__ out, const float* __restrict__ flag)
{
    bool isbf = flag[0] != 0.f;
    const void* Ws[6] = {W0, W1, W2, W3, W4, W5};
    const int   din[6] = {192, 256, 256, 160, 192, 192};
    int mtx = blockIdx.x >> 3;
    int off = 0;
    for (int i = 0; i < mtx; i++) off += 64 * din[i];
    int d = din[mtx];
    const void* W = Ws[mtx];
    for (int i = (blockIdx.x & 7) * 256 + threadIdx.x; i < 64 * d; i += 8 * 256) {
        int n = i / d, k = i % d;
        out[off + n * d + k] = f2bs(ldv(W, (size_t)k * 64 + n, isbf));
    }
}

// ---------------- Edge MLP via MFMA: LDS-staged swizzled Wt + 2-deep pipelined persistent tiles ----------------
template<bool L0>
__global__ __launch_bounds__(256, 4) void edge_mfma(
    const int* __restrict__ ei, const int* __restrict__ batchv,
    const short* __restrict__ xb,
    const void* __restrict__ ein, size_t ein_off,
    const float* __restrict__ estats, const void* __restrict__ egamma, const void* __restrict__ ebeta,
    const short* __restrict__ ub,
    const short* __restrict__ Wt, const void* __restrict__ biasv,
    void* __restrict__ eout, size_t eout_off,
    int E, const float* __restrict__ flag,
    int ein_force_bf, int eout_force_bf, short* __restrict__ eout2)
{
    constexpr int DIN = L0 ? 192 : 256;
    constexpr int NQ = DIN / 32;
    constexpr int ROWB = DIN * 2;           // bytes per Wt row
    __shared__ __align__(16) char Wl[64 * ROWB];   // 24KB (L0) / 32KB
    __shared__ __align__(16) char T[4 * 2048];     // swizzled epilogue transpose, 8KB
    const bool isbf = flag[0] != 0.f;
    const bool ein_bf = ein_force_bf ? true : isbf;
    const bool eout_bf = eout_force_bf ? true : isbf;
    const int w = threadIdx.x >> 6, j = threadIdx.x & 63;
    const int m16 = j & 15, c8v = j >> 4, c8 = c8v * 8;
    const int rr8 = j >> 3, cc8 = j & 7;

    // stage Wt -> LDS, XOR-swizzled (byte ^= (row&7)<<4)
    for (int i = threadIdx.x; i < DIN * 8; i += 256) {
        int lin = i * 16;
        int row = i / (DIN / 8);
        *(short8*)(Wl + (lin ^ ((row & 7) << 4))) = *(const short8*)(Wt + i * 8);
    }
    __syncthreads();

    char* Tw = T + w * 2048;
    const int wkey = (m16 & 7) << 4;

    // loop-invariant BN constants (L0) and bias
    float sc[8], sh[8];
    if constexpr (L0) {
        #pragma unroll
        for (int k = 0; k < 8; k++) {
            int col = c8 + k;
            float m = estats[col] / (float)E;
            float iv = rsqrtf(estats[32 + col] / (float)E - m * m + EPS);
            sc[k] = ldv(egamma, col, isbf) * iv;
            sh[k] = ldv(ebeta, col, isbf) - m * sc[k];
        }
    }
    float bc[4];
    #pragma unroll
    for (int t = 0; t < 4; t++) bc[t] = ldv(biasv, t * 16 + m16, isbf);

    const int ntiles = (E + 63) >> 6;
    const int gs = gridDim.x;
    int tile = blockIdx.x;
    if (tile >= ntiles) return;   // no barriers past this point

    auto ldidx = [&](int t, int& s_, int& d_, int& ec_) {
        int e_ = t * 64 + w * 16 + m16; if (e_ > E - 1) e_ = E - 1;
        ec_ = e_; s_ = ei[e_]; d_ = ei[E + e_];
    };
    auto issue = [&](int s_, int d_, int ec_, int g_, RawE& R) {
        R.x0 = ld16s(xb + (size_t)s_ * 64 + c8);
        R.x1 = ld16s(xb + (size_t)s_ * 64 + 32 + c8);
        R.x2 = ld16s(xb + (size_t)d_ * 64 + c8);
        R.x3 = ld16s(xb + (size_t)d_ * 64 + 32 + c8);
        if constexpr (L0) {
            if (isbf) {
                R.eA = ld16s((const short*)ein + (size_t)ec_ * 32 + c8);
            } else {
                const float* ef = (const float*)ein + (size_t)ec_ * 32 + c8;
                R.f0 = *(const float4*)ef; R.f1 = *(const float4*)(ef + 4);
            }
            R.u0 = ld16s(ub + (size_t)g_ * 32 + c8);
        } else {
            if (ein_bf) {
                R.eA = ld16s((const short*)ein + ein_off + (size_t)ec_ * 64 + c8);
                R.eB = ld16s((const short*)ein + ein_off + (size_t)ec_ * 64 + 32 + c8);
            } else {
                const float* ef = (const float*)ein + ein_off + (size_t)ec_ * 64;
                R.f0 = *(const float4*)(ef + c8);      R.f1 = *(const float4*)(ef + c8 + 4);
                R.f2 = *(const float4*)(ef + 32 + c8); R.f3 = *(const float4*)(ef + 36 + c8);
            }
            R.u0 = ld16s(ub + (size_t)g_ * 64 + c8);
            R.u1 = ld16s(ub + (size_t)g_ * 64 + 32 + c8);
        }
    };
    auto fin = [&](const RawE& R, short8* af) {
        af[0] = R.x0; af[1] = R.x1; af[2] = R.x2; af[3] = R.x3;
        if constexpr (L0) {
            float ev[8];
            if (isbf) {
                #pragma unroll
                for (int k = 0; k < 8; k++) ev[k] = bs2f(R.eA[k]);
            } else {
                ev[0]=R.f0.x; ev[1]=R.f0.y; ev[2]=R.f0.z; ev[3]=R.f0.w;
                ev[4]=R.f1.x; ev[5]=R.f1.y; ev[6]=R.f1.z; ev[7]=R.f1.w;
            }
            #pragma unroll
            for (int k = 0; k < 8; k++) af[4][k] = f2bs(ev[k] * sc[k] + sh[k]);
            af[5] = R.u0;
        } else {
            if (ein_bf) { af[4] = R.eA; af[5] = R.eB; }
            else {
                af[4][0]=f2bs(R.f0.x); af[4][1]=f2bs(R.f0.y); af[4][2]=f2bs(R.f0.z); af[4][3]=f2bs(R.f0.w);
                af[4][4]=f2bs(R.f1.x); af[4][5]=f2bs(R.f1.y); af[4][6]=f2bs(R.f1.z); af[4][7]=f2bs(R.f1.w);
                af[5][0]=f2bs(R.f2.x); af[5][1]=f2bs(R.f2.y); af[5][2]=f2bs(R.f2.z); af[5][3]=f2bs(R.f2.w);
                af[5][4]=f2bs(R.f3.x); af[5][5]=f2bs(R.f3.y); af[5][6]=f2bs(R.f3.z); af[5][7]=f2bs(R.f3.w);
            }
            af[6] = R.u0; af[7] = R.u1;
        }
    };

    // ---- pipeline prologue: frags for tile, idx for tile+gs ----
    short8 af[NQ];
    int sN = 0, dN = 0, ecN = 0;
    {
        RawE R;
        int s0, d0, ec0;
        ldidx(tile, s0, d0, ec0);
        int g0 = batchv[s0];
        issue(s0, d0, ec0, g0, R);
        fin(R, af);                       // one exposed latency per block
        int t2 = tile + gs;
        if (t2 < ntiles) ldidx(t2, sN, dN, ecN);
    }

    for (; tile < ntiles; tile += gs) {
        const int tn = tile + gs;
        const bool hasN = tn < ntiles;
        RawE Rn; int gN = 0;
        if (hasN) { gN = batchv[sN]; issue(sN, dN, ecN, gN, Rn); }   // in flight across MFMA+epilogue
        const int tnn = tn + gs;
        int sQ = 0, dQ = 0, ecQ = 0;
        if (tnn < ntiles) ldidx(tnn, sQ, dQ, ecQ);

        f32x4 acc[4] = {{0,0,0,0},{0,0,0,0},{0,0,0,0},{0,0,0,0}};
        #pragma unroll
        for (int q = 0; q < NQ; q++) {
            #pragma unroll
            for (int t = 0; t < 4; t++) {
                int lin = (t * 16 + m16) * ROWB + q * 64 + c8v * 16;
                short8 bv = *(const short8*)(Wl + (lin ^ wkey));
                acc[t] = __builtin_amdgcn_mfma_f32_16x16x32_bf16(af[q], bv, acc[t], 0, 0, 0);
            }
        }

        // epilogue: wave-private swizzled LDS transpose -> coalesced row stores
        const int we = tile * 64 + w * 16;
        #pragma unroll
        for (int t = 0; t < 4; t++) {
            #pragma unroll
            for (int r = 0; r < 4; r++) {
                float v = fmaxf(acc[t][r] + bc[t], 0.f);
                int rr = c8v * 4 + r;
                int lin = rr * 128 + (t * 16 + m16) * 2;
                *(short*)(Tw + (lin ^ ((rr & 7) << 4))) = f2bs(v);
            }
        }
        #pragma unroll
        for (int i = 0; i < 2; i++) {
            int r = i * 8 + rr8;
            int e2 = we + r;
            if (e2 < E) {
                short8 row = *(const short8*)(Tw + ((r * 128 + cc8 * 16) ^ ((rr8 & 7) << 4)));
                if (eout_bf) {
                    *(short8*)((short*)eout + eout_off + (size_t)e2 * 64 + cc8 * 8) = row;
                } else {
                    float* op = (float*)eout + eout_off + (size_t)e2 * 64 + cc8 * 8;
                    float4 a, b;
                    a.x=bs2f(row[0]); a.y=bs2f(row[1]); a.z=bs2f(row[2]); a.w=bs2f(row[3]);
                    b.x=bs2f(row[4]); b.y=bs2f(row[5]); b.z=bs2f(row[6]); b.w=bs2f(row[7]);
                    *(float4*)op = a; *(float4*)(op + 4) = b;
                }
                if (eout2) {
                    *(short8*)(eout2 + (size_t)e2 * 64 + cc8 * 8) = row;
                }
            }
        }

        // rotate pipeline state
        if (hasN) fin(Rn, af);
        if (tnn < ntiles) { sN = sQ; dN = dQ; ecN = ecQ; }
    }
}

// ---------------- Node MLP: LDS-staged swizzled Wt + pipelined in-register CSR agg-mean ----------------
template<bool L0, bool FINAL>
__global__ __launch_bounds__(256, 4) void node_fused(
    const int* __restrict__ batchv, const short* __restrict__ xin,
    const int* __restrict__ off, const int* __restrict__ csr, const int* __restrict__ cntv,
    const void* __restrict__ eout, size_t eoff,
    const short* __restrict__ ub,
    const short* __restrict__ Wt, const void* __restrict__ biasv,
    short* __restrict__ xoutb, void* __restrict__ dout, int N,
    const float* __restrict__ flag, int e_force_bf)
{
    constexpr int DIN = L0 ? 160 : 192;
    constexpr int NQ = DIN / 32;
    constexpr int ROWB = DIN * 2;           // 320 (L0) / 384 bytes per row
    __shared__ __align__(16) char Wl[64 * ROWB];   // 20KB / 24KB
    __shared__ __align__(16) char T[4 * 2048];     // 8KB
    const bool isbf = flag[0] != 0.f;
    const bool e_bf = e_force_bf ? true : isbf;
    const int w = threadIdx.x >> 6, j = threadIdx.x & 63;
    const int m16 = j & 15, c8v = j >> 4, c8 = c8v * 8;
    const int rr8 = j >> 3, cc8 = j & 7;
    const int nb = blockIdx.x * 64 + w * 16;

    // stage Wt -> LDS, XOR-swizzled
    for (int i = threadIdx.x; i < DIN * 8; i += 256) {
        int lin = i * 16;
        int row = i / (DIN / 8);
        *(short8*)(Wl + (lin ^ ((row & 7) << 4))) = *(const short8*)(Wt + i * 8);
    }
    __syncthreads();

    char* Tw = T + w * 2048;
    const int wkey = (m16 & 7) << 4;

    int n = nb + m16; if (n > N - 1) n = N - 1;
    int g = batchv[n];

    short8 af[NQ];
    af[0] = ld16s(xin + (size_t)n * 64 + c8);
    af[1] = ld16s(xin + (size_t)n * 64 + 32 + c8);

    // agg-mean for row n, cols c8..c8+7 and 32+c8..+7, straight into fragments
    {
        int st = off[n], c = cntv[n];
        float s0[8] = {0,0,0,0,0,0,0,0}, s1[8] = {0,0,0,0,0,0,0,0};
        if (e_bf) {
            const short* ep = (const short*)eout + eoff;
            int npairs = c >> 1;
            if (npairs > 0) {
                // 3-stage pipeline: idx(p+2) / rows(p+1) / sum(p)
                int iA0 = csr[st], iA1 = csr[st + 1];
                short8 rA0 = ld16s(ep + (size_t)iA0 * 64 + c8);
                short8 qA0 = ld16s(ep + (size_t)iA0 * 64 + 32 + c8);
                short8 rA1 = ld16s(ep + (size_t)iA1 * 64 + c8);
                short8 qA1 = ld16s(ep + (size_t)iA1 * 64 + 32 + c8);
                int aB = (1 < npairs) ? st + 2 : st;
                int iB0 = csr[aB], iB1 = csr[aB + 1];
                for (int p = 0; p < npairs; p++) {
                    int aC = (p + 2 < npairs) ? st + 2 * (p + 2) : st;  // clamped: valid addr, never summed
                    int iC0 = csr[aC], iC1 = csr[aC + 1];
                    short8 rB0 = ld16s(ep + (size_t)iB0 * 64 + c8);
                    short8 qB0 = ld16s(ep + (size_t)iB0 * 64 + 32 + c8);
                    short8 rB1 = ld16s(ep + (size_t)iB1 * 64 + c8);
                    short8 qB1 = ld16s(ep + (size_t)iB1 * 64 + 32 + c8);
                    #pragma unroll
                    for (int k = 0; k < 8; k++) {
                        s0[k] += bs2f(rA0[k]) + bs2f(rA1[k]);
                        s1[k] += bs2f(qA0[k]) + bs2f(qA1[k]);
                    }
                    rA0 = rB0; qA0 = qB0; rA1 = rB1; qA1 = qB1;
                    iB0 = iC0; iB1 = iC1;
                }
            }
            if (c & 1) {
                int e0 = csr[st + c - 1];
                short8 r0 = ld16s(ep + (size_t)e0 * 64 + c8);
                short8 q0 = ld16s(ep + (size_t)e0 * 64 + 32 + c8);
                #pragma unroll
                for (int k = 0; k < 8; k++) { s0[k] += bs2f(r0[k]); s1[k] += bs2f(q0[k]); }
            }
        } else {
            const float* ep = (const float*)eout + eoff;
            for (int t = 0; t < c; t++) {
                int e0 = csr[st + t];
                const float* rp = ep + (size_t)e0 * 64;
                float4 a = *(const float4*)(rp + c8), b = *(const float4*)(rp + c8 + 4);
                float4 x = *(const float4*)(rp + 32 + c8), y = *(const float4*)(rp + 36 + c8);
                s0[0]+=a.x; s0[1]+=a.y; s0[2]+=a.z; s0[3]+=a.w; s0[4]+=b.x; s0[5]+=b.y; s0[6]+=b.z; s0[7]+=b.w;
                s1[0]+=x.x; s1[1]+=x.y; s1[2]+=x.z; s1[3]+=x.w; s1[4]+=y.x; s1[5]+=y.y; s1[6]+=y.z; s1[7]+=y.w;
            }
        }
        float rc = 1.0f / fmaxf((float)c, 1.0f);
        #pragma unroll
        for (int k = 0; k < 8; k++) { af[2][k] = f2bs(s0[k] * rc); af[3][k] = f2bs(s1[k] * rc); }
    }

    if constexpr (L0) {
        af[4] = ld16s(ub + (size_t)g * 32 + c8);          // u 32-wide
    } else {
        af[4] = ld16s(ub + (size_t)g * 64 + c8);
        af[5] = ld16s(ub + (size_t)g * 64 + 32 + c8);
    }

    f32x4 acc[4] = {{0,0,0,0},{0,0,0,0},{0,0,0,0},{0,0,0,0}};
    #pragma unroll
    for (int q = 0; q < NQ; q++) {
        #pragma unroll
        for (int t = 0; t < 4; t++) {
            int lin = (t * 16 + m16) * ROWB + q * 64 + c8v * 16;
            short8 bv = *(const short8*)(Wl + (lin ^ wkey));
            acc[t] = __builtin_amdgcn_mfma_f32_16x16x32_bf16(af[q], bv, acc[t], 0, 0, 0);
        }
    }

    #pragma unroll
    for (int t = 0; t < 4; t++) {
        float bcv = ldv(biasv, t * 16 + m16, isbf);
        #pragma unroll
        for (int r = 0; r < 4; r++) {
            float v = fmaxf(acc[t][r] + bcv, 0.f);
            int rr = c8v * 4 + r;
            int lin = rr * 128 + (t * 16 + m16) * 2;
            *(short*)(Tw + (lin ^ ((rr & 7) << 4))) = f2bs(v);
        }
    }
    #pragma unroll
    for (int i = 0; i < 2; i++) {
        int r = i * 8 + rr8;
        int n2 = nb + r;
        if (n2 < N) {
            short8 row = *(const short8*)(Tw + ((r * 128 + cc8 * 16) ^ ((rr8 & 7) << 4)));
            *(short8*)&xoutb[(size_t)n2 * 64 + cc8 * 8] = row;
            if (FINAL) {
                if (isbf) {
                    *(short8*)((short*)dout + (size_t)n2 * 64 + cc8 * 8) = row;
                } else {
                    float* op = (float*)dout + (size_t)n2 * 64 + cc8 * 8;
                    float4 a, b;
                    a.x=bs2f(row[0]); a.y=bs2f(row[1]); a.z=bs2f(row[2]); a.w=bs2f(row[3]);
                    b.x=bs2f(row[4]); b.y=bs2f(row[5]); b.z=bs2f(row[6]); b.w=bs2f(row[7]);
                    *(float4*)op = a; *(float4*)(op + 4) = b;
                }
            }
        }
    }
}

// ---------------- per-graph pooling: 8 blocks per graph ----------------
__global__ __launch_bounds__(256) void pool_kernel(const int* __restrict__ gstart,
                                                   const short* __restrict__ xb,
                                                   float* __restrict__ gsum) {
    int g = blockIdx.x >> 3, slice = blockIdx.x & 7;
    int st = gstart[g], en = gstart[g + 1];
    int len = en - st;
    int K = (len + 7) >> 3;
    int b0 = st + slice * K;
    int b1 = min(b0 + K, en);
    int rg = threadIdx.x >> 3, cc8 = threadIdx.x & 7;
    float a[8] = {0,0,0,0,0,0,0,0};
    for (int r = b0 + rg; r < b1; r += 32) {
        short8 v = *(const short8*)&xb[(size_t)r * 64 + cc8 * 8];
        #pragma unroll
        for (int k = 0; k < 8; k++) a[k] += bs2f(v[k]);
    }
    __shared__ float sm[32][64];
    #pragma unroll
    for (int k = 0; k < 8; k++) sm[rg][cc8 * 8 + k] = a[k];
    __syncthreads();
    if (threadIdx.x < 64) {
        float s = 0.f;
        #pragma unroll 8
        for (int q = 0; q < 32; q++) s += sm[q][threadIdx.x];
        atomicAdd(&gsum[g * 64 + threadIdx.x], s);
    }
}

// ---------------- Global MLP GEMM: wave per graph ----------------
template<int FU>
__global__ __launch_bounds__(256) void glob_gemm(
    const int* __restrict__ gstart, const float* __restrict__ gsum,
    const float* __restrict__ uin,
    const void* __restrict__ W, const void* __restrict__ biasv,
    float* __restrict__ uoutf, short* __restrict__ uoutb,
    const float* __restrict__ flag)
{
    bool isbf = flag[0] != 0.f;
    const int DIN = 64 + FU;
    __shared__ float s[4][192];
    int w = threadIdx.x >> 6, j = threadIdx.x & 63;
    int g = blockIdx.x * 4 + w;
    int st = gstart[g], en = gstart[g + 1];
    float rc = 1.0f / fmaxf((float)(en - st), 1.0f);
    s[w][j] = gsum[g * 64 + j] * rc;
    if (j < FU) s[w][64 + j] = uin[g * FU + j];
    float acc = ldv(biasv, j, isbf);
    for (int k = 0; k < DIN; k++) acc += s[w][k] * ldv(W, (size_t)k * 64 + j, isbf);
    acc = fmaxf(acc, 0.f);
    uoutf[g * 64 + j] = acc;
    uoutb[g * 64 + j] = f2bs(acc);
}

// ---------------- cast f32 ws -> d_out region ----------------
__global__ __launch_bounds__(256) void cast_out(const float* __restrict__ in, void* __restrict__ out,
                                                size_t out_off, int n, const float* __restrict__ flag) {
    bool isbf = flag[0] != 0.f;
    for (int i = blockIdx.x * 256 + threadIdx.x; i < n; i += gridDim.x * 256)
        stv(out, out_off + i, in[i], isbf);
}

extern "C" void kernel_launch(void* const* d_in, const int* in_sizes, int n_in,
                              void* d_out, int out_size, void* d_ws, size_t ws_size,
                              hipStream_t stream) {
    const void* x_in   = d_in[0];
    const int*  ei     = (const int*)d_in[1];
    const void* e_raw  = d_in[2];
    const void* u_raw  = d_in[3];
    const int*  batchv = (const int*)d_in[4];
    const void *g_node = d_in[5],  *b_node = d_in[6];
    const void *g_edge = d_in[7],  *b_edge = d_in[8];
    const void *g_glob = d_in[9],  *b_glob = d_in[10];
    const void* We[3] = {d_in[11], d_in[17], d_in[23]};
    const void* be[3] = {d_in[12], d_in[18], d_in[24]};
    const void* Wn[3] = {d_in[13], d_in[19], d_in[25]};
    const void* bn[3] = {d_in[14], d_in[20], d_in[26]};
    const void* Wg[3] = {d_in[15], d_in[21], d_in[27]};
    const void* bg[3] = {d_in[16], d_in[22], d_in[28]};

    const int N = in_sizes[0] / 64;   // 30000
    const int E = in_sizes[2] / 32;   // 300000
    const int B = in_sizes[3] / 32;   // 64

    // ---- workspace: contiguous zero-region first (single memset) ----
    float* p = (float*)d_ws;
    float* zbase  = p;
    float* stats  = p; p += 3 * 128;
    int*   cursor = (int*)p; p += 4;
    int*   cnt    = (int*)p; p += N;
    float* gsum0  = p; p += B * 64;
    float* gsum1  = p; p += B * 64;
    float* gsum2  = p; p += B * 64;
    size_t zbytes = (size_t)((char*)p - (char*)zbase);
    float* dflag  = p; p += 4;
    float* uN     = p; p += B * 32;
    float* uA     = p; p += B * 64;
    float* uB     = p; p += B * 64;
    int*   off    = (int*)p; p += N;
    int*   wcur   = (int*)p; p += N;
    int*   gstart = (int*)p; p += 72;
    int*   csr    = (int*)p; p += E;
    short* xb0    = (short*)p; p += (size_t)N * 32;
    short* xb1    = (short*)p; p += (size_t)N * 32;
    short* ubN    = (short*)p; p += B * 16;
    short* ubA    = (short*)p; p += B * 32;
    short* ubB    = (short*)p; p += B * 32;
    short* WtAll  = (short*)p; p += 79872 / 2;
    const short* WtE0 = WtAll;
    const short* WtE1 = WtAll + 12288;
    const short* WtE2 = WtAll + 28672;
    const short* WtN0 = WtAll + 45056;
    const short* WtN1 = WtAll + 55296;
    const short* WtN2 = WtAll + 67584;

    // bf16 intermediate-e buffer (E x 64 shorts), if workspace has room
    short* eb16 = nullptr;
    {
        size_t used = (size_t)((char*)p - (char*)d_ws);
        used = (used + 15) & ~(size_t)15;
        size_t need = used + (size_t)E * 64 * sizeof(short);
        if (ws_size >= need) eb16 = (short*)((char*)d_ws + used);
    }

    const size_t EOFF = (size_t)N * 64;
    const size_t UOFF = EOFF + (size_t)E * 64;

    hipMemsetAsync(zbase, 0, zbytes, stream);

    detect_dtype<<<1, 256, 0, stream>>>((const unsigned short*)x_in, dflag);

    bn_stats<64><<<256, 256, 0, stream>>>(x_in, N, stats, dflag);
    bn_stats<32><<<512, 256, 0, stream>>>(e_raw, E, stats + 128, dflag);
    bn_stats<32><<<8,   256, 0, stream>>>(u_raw, B, stats + 256, dflag);
    bn_apply_x<<<512, 256, 0, stream>>>(x_in, xb0, stats, N, g_node, b_node, dflag);
    bn_apply_u<<<8,   256, 0, stream>>>(u_raw, uN, ubN, stats + 256, B, g_glob, b_glob, dflag);
    count_kernel<<<512, 256, 0, stream>>>(ei, cnt, E);
    csr_offsets<<<(N + 255) / 256, 256, 0, stream>>>(cnt, off, wcur, cursor, N, batchv, gstart, B);
    csr_fill<<<512, 256, 0, stream>>>(ei, wcur, csr, E);
    transpose_w<<<48, 256, 0, stream>>>(We[0], We[1], We[2], Wn[0], Wn[1], Wn[2], WtAll, dflag);

    const int NG = (N + 63) / 64;   // 469
    const int NT = (E + 63) / 64;   // 4688 tiles
    const int EG0 = NT < 1280 ? NT : 1280;   // L0: 32KB LDS -> 5 blocks/CU
    const int EG  = NT < 1024 ? NT : 1024;   // L1/2: 40KB LDS -> 4 blocks/CU

    if (eb16) {
        // ---- bf16 intermediate-e flow ----
        // layer 0
        edge_mfma<true><<<EG0, 256, 0, stream>>>(
            ei, batchv, xb0, e_raw, 0, stats + 128, g_edge, b_edge,
            ubN, WtE0, be[0], eb16, 0, E, dflag, 0, 1, nullptr);
        node_fused<true, false><<<NG, 256, 0, stream>>>(
            batchv, xb0, off, csr, cnt, eb16, 0, ubN, WtN0, bn[0], xb1, nullptr, N, dflag, 1);
        pool_kernel<<<B * 8, 256, 0, stream>>>(gstart, xb1, gsum0);
        glob_gemm<32><<<B / 4, 256, 0, stream>>>(gstart, gsum0, uN, Wg[0], bg[0], uA, ubA, dflag);

        // layer 1 (e in-place bf16: wave-private row windows, safe)
        edge_mfma<false><<<EG, 256, 0, stream>>>(
            ei, batchv, xb1, eb16, 0, nullptr, nullptr, nullptr,
            ubA, WtE1, be[1], eb16, 0, E, dflag, 1, 1, nullptr);
        node_fused<false, false><<<NG, 256, 0, stream>>>(
            batchv, xb1, off, csr, cnt, eb16, 0, ubA, WtN1, bn[1], xb0, nullptr, N, dflag, 1);
        pool_kernel<<<B * 8, 256, 0, stream>>>(gstart, xb0, gsum1);
        glob_gemm<64><<<B / 4, 256, 0, stream>>>(gstart, gsum1, uA, Wg[1], bg[1], uB, ubB, dflag);

        // layer 2: final e -> d_out (input dtype) + bf16 copy for node gather
        edge_mfma<false><<<EG, 256, 0, stream>>>(
            ei, batchv, xb0, eb16, 0, nullptr, nullptr, nullptr,
            ubB, WtE2, be[2], d_out, EOFF, E, dflag, 1, 0, eb16);
        node_fused<false, true><<<NG, 256, 0, stream>>>(
            batchv, xb0, off, csr, cnt, eb16, 0, ubB, WtN2, bn[2], xb1, d_out, N, dflag, 1);
        pool_kernel<<<B * 8, 256, 0, stream>>>(gstart, xb1, gsum2);
        glob_gemm<64><<<B / 4, 256, 0, stream>>>(gstart, gsum2, uB, Wg[2], bg[2], uA, ubA, dflag);
    } else {
        // ---- fallback: original flow, e intermediate in d_out (input dtype) ----
        edge_mfma<true><<<EG0, 256, 0, stream>>>(
            ei, batchv, xb0, e_raw, 0, stats + 128, g_edge, b_edge,
            ubN, WtE0, be[0], d_out, EOFF, E, dflag, 0, 0, nullptr);
        node_fused<true, false><<<NG, 256, 0, stream>>>(
            batchv, xb0, off, csr, cnt, d_out, EOFF, ubN, WtN0, bn[0], xb1, nullptr, N, dflag, 0);
        pool_kernel<<<B * 8, 256, 0, stream>>>(gstart, xb1, gsum0);
        glob_gemm<32><<<B / 4, 256, 0, stream>>>(gstart, gsum0, uN, Wg[0], bg[0], uA, ubA, dflag);

        edge_mfma<false><<<EG, 256, 0, stream>>>(
            ei, batchv, xb1, d_out, EOFF, nullptr, nullptr, nullptr,
            ubA, WtE1, be[1], d_out, EOFF, E, dflag, 0, 0, nullptr);
        node_fused<false, false><<<NG, 256, 0, stream>>>(
            batchv, xb1, off, csr, cnt, d_out, EOFF, ubA, WtN1, bn[1], xb0, nullptr, N, dflag, 0);
        pool_kernel<<<B * 8, 256, 0, stream>>>(gstart, xb0, gsum1);
        glob_gemm<64><<<B / 4, 256, 0, stream>>>(gstart, gsum1, uA, Wg[1], bg[1], uB, ubB, dflag);

        edge_mfma<false><<<EG, 256, 0, stream>>>(
            ei, batchv, xb0, d_out, EOFF, nullptr, nullptr, nullptr,
            ubB, WtE2, be[2], d_out, EOFF, E, dflag, 0, 0, nullptr);
        node_fused<false, true><<<NG, 256, 0, stream>>>(
            batchv, xb0, off, csr, cnt, d_out, EOFF, ubB, WtN2, bn[2], xb1, d_out, N, dflag, 0);
        pool_kernel<<<B * 8, 256, 0, stream>>>(gstart, xb1, gsum2);
        glob_gemm<64><<<B / 4, 256, 0, stream>>>(gstart, gsum2, uB, Wg[2], bg[2], uA, ubA, dflag);
    }

    // ---- u output ----
    cast_out<<<16, 256, 0, stream>>>(uA, d_out, UOFF, B * 64, dflag);
}

// Round 5
// 481.201 us; speedup vs baseline: 1.7559x; 1.7559x over previous
//
#include <hip/hip_runtime.h>
#include <hip/hip_bf16.h>

#define EPS 1e-5f
typedef __hip_bfloat16 bf16;
typedef __attribute__((ext_vector_type(8))) short  short8;
typedef __attribute__((ext_vector_type(4))) float  f32x4;

__device__ __forceinline__ float b2f(bf16 v) { return __bfloat162float(v); }
__device__ __forceinline__ float bs2f(short s) { bf16 b = *reinterpret_cast<bf16*>(&s); return b2f(b); }
__device__ __forceinline__ float ldv(const void* p, size_t i, bool bf) {
    return bf ? b2f(((const bf16*)p)[i]) : ((const float*)p)[i];
}
__device__ __forceinline__ void stv(void* p, size_t i, float v, bool bf) {
    if (bf) ((bf16*)p)[i] = __float2bfloat16(v);
    else    ((float*)p)[i] = v;
}
__device__ __forceinline__ short f2bs(float v) {
    bf16 b = __float2bfloat16(v);
    return *reinterpret_cast<short*>(&b);
}
__device__ __forceinline__ short8 ld16s(const short* p) { return *(const short8*)p; }

// ---------------- dtype detector ----------------
__global__ void detect_dtype(const unsigned short* __restrict__ xs, float* __restrict__ flag) {
    __shared__ int cnt;
    if (threadIdx.x == 0) cnt = 0;
    __syncthreads();
    unsigned short u = xs[threadIdx.x];
    int e = (u >> 7) & 0xFF;
    int sane = (u == 0 || (e >= 110 && e <= 140)) ? 1 : 0;
    atomicAdd(&cnt, sane);
    __syncthreads();
    if (threadIdx.x == 0) flag[0] = (cnt >= 230) ? 1.0f : 0.0f;
}

// ---------------- BatchNorm stats ----------------
template<int C>
__global__ __launch_bounds__(256) void bn_stats(const void* __restrict__ in, int R,
                                                float* __restrict__ stats, const float* __restrict__ flag) {
    bool isbf = flag[0] != 0.f;
    const int RG = 256 / C;
    int c = threadIdx.x % C, rg = threadIdx.x / C;
    float s = 0.f, s2 = 0.f;
    if (isbf) {
        const bf16* ip = (const bf16*)in;
        for (int r = blockIdx.x * RG + rg; r < R; r += gridDim.x * RG) {
            float v = b2f(ip[(size_t)r * C + c]); s += v; s2 += v * v;
        }
    } else {
        const float* ip = (const float*)in;
        for (int r = blockIdx.x * RG + rg; r < R; r += gridDim.x * RG) {
            float v = ip[(size_t)r * C + c]; s += v; s2 += v * v;
        }
    }
    __shared__ float sm[2][256];
    sm[0][threadIdx.x] = s; sm[1][threadIdx.x] = s2;
    __syncthreads();
    if (threadIdx.x < C) {
        float ts = 0.f, t2 = 0.f;
        for (int g = 0; g < RG; g++) { ts += sm[0][g * C + c]; t2 += sm[1][g * C + c]; }
        atomicAdd(&stats[c], ts);
        atomicAdd(&stats[C + c], t2);
    }
}

// ---------------- BN apply: x -> bf16 internal ----------------
__global__ __launch_bounds__(256) void bn_apply_x(const void* __restrict__ in, short* __restrict__ out,
                                                  const float* __restrict__ stats, int R,
                                                  const void* __restrict__ gamma, const void* __restrict__ beta,
                                                  const float* __restrict__ flag) {
    bool isbf = flag[0] != 0.f;
    int total = R * 64;
    for (int i = blockIdx.x * 256 + threadIdx.x; i < total; i += gridDim.x * 256) {
        int c = i & 63;
        float mean = stats[c] / (float)R;
        float var = stats[64 + c] / (float)R - mean * mean;
        float inv = rsqrtf(var + EPS);
        out[i] = f2bs(ldv(gamma, c, isbf) * (ldv(in, i, isbf) - mean) * inv + ldv(beta, c, isbf));
    }
}

// ---------------- BN apply: u -> f32 + bf16 tables ----------------
__global__ __launch_bounds__(256) void bn_apply_u(const void* __restrict__ in, float* __restrict__ outf,
                                                  short* __restrict__ outb,
                                                  const float* __restrict__ stats, int R,
                                                  const void* __restrict__ gamma, const void* __restrict__ beta,
                                                  const float* __restrict__ flag) {
    bool isbf = flag[0] != 0.f;
    int total = R * 32;
    for (int i = blockIdx.x * 256 + threadIdx.x; i < total; i += gridDim.x * 256) {
        int c = i & 31;
        float mean = stats[c] / (float)R;
        float var = stats[32 + c] / (float)R - mean * mean;
        float inv = rsqrtf(var + EPS);
        float v = ldv(gamma, c, isbf) * (ldv(in, i, isbf) - mean) * inv + ldv(beta, c, isbf);
        outf[i] = v; outb[i] = f2bs(v);
    }
}

// ---------------- per-dst edge counts ----------------
__global__ __launch_bounds__(256) void count_kernel(const int* __restrict__ ei, int* __restrict__ cnt, int E) {
    int stride = gridDim.x * 256;
    for (int t = blockIdx.x * 256 + threadIdx.x; t < E; t += stride) atomicAdd(&cnt[ei[E + t]], 1);
}

// ---------------- CSR offsets + per-graph ranges (merged) ----------------
__global__ __launch_bounds__(256) void csr_offsets(const int* __restrict__ cnt, int* __restrict__ off,
                                                   int* __restrict__ wcur, int* __restrict__ cursor, int N,
                                                   const int* __restrict__ batch, int* __restrict__ gstart, int B) {
    int n = blockIdx.x * 256 + threadIdx.x;
    if (n < N) {
        int o = atomicAdd(cursor, cnt[n]);
        off[n] = o; wcur[n] = o;
    }
    if (blockIdx.x == 0 && threadIdx.x <= B) {
        int t = threadIdx.x;
        int lo = 0, hi = N;
        while (lo < hi) { int mid = (lo + hi) >> 1; if (batch[mid] < t) lo = mid + 1; else hi = mid; }
        gstart[t] = lo;
    }
}

__global__ __launch_bounds__(256) void csr_fill(const int* __restrict__ ei, int* __restrict__ wcur,
                                                int* __restrict__ csr, int E) {
    int stride = gridDim.x * 256;
    for (int t = blockIdx.x * 256 + threadIdx.x; t < E; t += stride) {
        int d = ei[E + t];
        int pos = atomicAdd(&wcur[d], 1);
        csr[pos] = t;
    }
}

// ---------------- W transpose prep ----------------
__global__ __launch_bounds__(256) void transpose_w(
    const void* __restrict__ W0, const void* __restrict__ W1, const void* __restrict__ W2,
    const void* __restrict__ W3, const void* __restrict__ W4, const void* __restrict__ W5,
    short* __restrict__ out, const float* __restrict__ flag)
{
    bool isbf = flag[0] != 0.f;
    const void* Ws[6] = {W0, W1, W2, W3, W4, W5};
    const int   din[6] = {192, 256, 256, 160, 192, 192};
    int mtx = blockIdx.x >> 3;
    int off = 0;
    for (int i = 0; i < mtx; i++) off += 64 * din[i];
    int d = din[mtx];
    const void* W = Ws[mtx];
    for (int i = (blockIdx.x & 7) * 256 + threadIdx.x; i < 64 * d; i += 8 * 256) {
        int n = i / d, k = i % d;
        out[off + n * d + k] = f2bs(ldv(W, (size_t)k * 64 + n, isbf));
    }
}

// ---------------- Edge MLP via MFMA: LDS-staged swizzled Wt + persistent tiles + idx-only prefetch ----------------
template<bool L0>
__global__ __launch_bounds__(256) void edge_mfma(
    const int* __restrict__ ei, const int* __restrict__ batchv,
    const short* __restrict__ xb,
    const void* __restrict__ ein, size_t ein_off,
    const float* __restrict__ estats, const void* __restrict__ egamma, const void* __restrict__ ebeta,
    const short* __restrict__ ub,
    const short* __restrict__ Wt, const void* __restrict__ biasv,
    void* __restrict__ eout, size_t eout_off,
    int E, const float* __restrict__ flag,
    int ein_force_bf, int eout_force_bf, short* __restrict__ eout2)
{
    constexpr int DIN = L0 ? 192 : 256;
    constexpr int NQ = DIN / 32;
    constexpr int ROWB = DIN * 2;           // bytes per Wt row
    __shared__ __align__(16) char Wl[64 * ROWB];   // 24KB (L0) / 32KB
    __shared__ __align__(16) char T[4 * 2048];     // swizzled epilogue transpose, 8KB
    const bool isbf = flag[0] != 0.f;
    const bool ein_bf = ein_force_bf ? true : isbf;
    const bool eout_bf = eout_force_bf ? true : isbf;
    const int w = threadIdx.x >> 6, j = threadIdx.x & 63;
    const int m16 = j & 15, c8v = j >> 4, c8 = c8v * 8;
    const int rr8 = j >> 3, cc8 = j & 7;

    // stage Wt -> LDS, XOR-swizzled (byte ^= (row&7)<<4)
    for (int i = threadIdx.x; i < DIN * 8; i += 256) {
        int lin = i * 16;
        int row = i / (DIN / 8);
        *(short8*)(Wl + (lin ^ ((row & 7) << 4))) = *(const short8*)(Wt + i * 8);
    }
    __syncthreads();

    char* Tw = T + w * 2048;
    const int wkey = (m16 & 7) << 4;

    // loop-invariant BN constants (L0) and bias
    float sc[8], sh[8];
    if constexpr (L0) {
        #pragma unroll
        for (int k = 0; k < 8; k++) {
            int col = c8 + k;
            float m = estats[col] / (float)E;
            float iv = rsqrtf(estats[32 + col] / (float)E - m * m + EPS);
            sc[k] = ldv(egamma, col, isbf) * iv;
            sh[k] = ldv(ebeta, col, isbf) - m * sc[k];
        }
    }
    float bc[4];
    #pragma unroll
    for (int t = 0; t < 4; t++) bc[t] = ldv(biasv, t * 16 + m16, isbf);

    const int ntiles = (E + 63) >> 6;
    const int gs = gridDim.x;
    int tile = blockIdx.x;
    if (tile < ntiles) {
        // idx prefetch state: 3 VGPRs only (lesson from R4 spill regression)
        int ec = tile * 64 + w * 16 + m16; if (ec > E - 1) ec = E - 1;
        int s = ei[ec], d = ei[E + ec];
        for (; tile < ntiles; tile += gs) {
            const int ecC = ec, sC = s, dC = d;
            const int tn = tile + gs;
            if (tn < ntiles) {          // issue next-tile index loads now; consumed next iteration
                int e2 = tn * 64 + w * 16 + m16; if (e2 > E - 1) e2 = E - 1;
                ec = e2; s = ei[e2]; d = ei[E + e2];
            }
            int g = batchv[sC];

            short8 af[NQ];
            af[0] = ld16s(xb + (size_t)sC * 64 + c8);
            af[1] = ld16s(xb + (size_t)sC * 64 + 32 + c8);
            af[2] = ld16s(xb + (size_t)dC * 64 + c8);
            af[3] = ld16s(xb + (size_t)dC * 64 + 32 + c8);
            if constexpr (L0) {
                float ev[8];
                if (isbf) {
                    short8 r = ld16s((const short*)ein + (size_t)ecC * 32 + c8);
                    #pragma unroll
                    for (int k = 0; k < 8; k++) ev[k] = bs2f(r[k]);
                } else {
                    const float* ef = (const float*)ein + (size_t)ecC * 32 + c8;
                    float4 a = *(const float4*)ef, b = *(const float4*)(ef + 4);
                    ev[0]=a.x; ev[1]=a.y; ev[2]=a.z; ev[3]=a.w; ev[4]=b.x; ev[5]=b.y; ev[6]=b.z; ev[7]=b.w;
                }
                #pragma unroll
                for (int k = 0; k < 8; k++) af[4][k] = f2bs(ev[k] * sc[k] + sh[k]);
                af[5] = ld16s(ub + (size_t)g * 32 + c8);          // u is 32-wide in layer 0
            } else {
                if (ein_bf) {
                    af[4] = ld16s((const short*)ein + ein_off + (size_t)ecC * 64 + c8);
                    af[5] = ld16s((const short*)ein + ein_off + (size_t)ecC * 64 + 32 + c8);
                } else {
                    const float* ef = (const float*)ein + ein_off + (size_t)ecC * 64;
                    float4 a = *(const float4*)(ef + c8), b = *(const float4*)(ef + c8 + 4);
                    af[4][0]=f2bs(a.x); af[4][1]=f2bs(a.y); af[4][2]=f2bs(a.z); af[4][3]=f2bs(a.w);
                    af[4][4]=f2bs(b.x); af[4][5]=f2bs(b.y); af[4][6]=f2bs(b.z); af[4][7]=f2bs(b.w);
                    a = *(const float4*)(ef + 32 + c8); b = *(const float4*)(ef + 36 + c8);
                    af[5][0]=f2bs(a.x); af[5][1]=f2bs(a.y); af[5][2]=f2bs(a.z); af[5][3]=f2bs(a.w);
                    af[5][4]=f2bs(b.x); af[5][5]=f2bs(b.y); af[5][6]=f2bs(b.z); af[5][7]=f2bs(b.w);
                }
                af[6] = ld16s(ub + (size_t)g * 64 + c8);
                af[7] = ld16s(ub + (size_t)g * 64 + 32 + c8);
            }

            f32x4 acc[4] = {{0,0,0,0},{0,0,0,0},{0,0,0,0},{0,0,0,0}};
            #pragma unroll
            for (int q = 0; q < NQ; q++) {
                #pragma unroll
                for (int t = 0; t < 4; t++) {
                    int lin = (t * 16 + m16) * ROWB + q * 64 + c8v * 16;
                    short8 bv = *(const short8*)(Wl + (lin ^ wkey));
                    acc[t] = __builtin_amdgcn_mfma_f32_16x16x32_bf16(af[q], bv, acc[t], 0, 0, 0);
                }
            }

            // epilogue: wave-private swizzled LDS transpose -> coalesced row stores
            const int we = tile * 64 + w * 16;
            #pragma unroll
            for (int t = 0; t < 4; t++) {
                #pragma unroll
                for (int r = 0; r < 4; r++) {
                    float v = fmaxf(acc[t][r] + bc[t], 0.f);
                    int rr = c8v * 4 + r;
                    int lin = rr * 128 + (t * 16 + m16) * 2;
                    *(short*)(Tw + (lin ^ ((rr & 7) << 4))) = f2bs(v);
                }
            }
            #pragma unroll
            for (int i = 0; i < 2; i++) {
                int r = i * 8 + rr8;
                int e2 = we + r;
                if (e2 < E) {
                    short8 row = *(const short8*)(Tw + ((r * 128 + cc8 * 16) ^ ((rr8 & 7) << 4)));
                    if (eout_bf) {
                        *(short8*)((short*)eout + eout_off + (size_t)e2 * 64 + cc8 * 8) = row;
                    } else {
                        float* op = (float*)eout + eout_off + (size_t)e2 * 64 + cc8 * 8;
                        float4 a, b;
                        a.x=bs2f(row[0]); a.y=bs2f(row[1]); a.z=bs2f(row[2]); a.w=bs2f(row[3]);
                        b.x=bs2f(row[4]); b.y=bs2f(row[5]); b.z=bs2f(row[6]); b.w=bs2f(row[7]);
                        *(float4*)op = a; *(float4*)(op + 4) = b;
                    }
                    if (eout2) {
                        *(short8*)(eout2 + (size_t)e2 * 64 + cc8 * 8) = row;
                    }
                }
            }
        }
    }
}

// ---------------- Node MLP: LDS-staged swizzled Wt + in-register CSR agg-mean ----------------
template<bool L0, bool FINAL>
__global__ __launch_bounds__(256) void node_fused(
    const int* __restrict__ batchv, const short* __restrict__ xin,
    const int* __restrict__ off, const int* __restrict__ csr, const int* __restrict__ cntv,
    const void* __restrict__ eout, size_t eoff,
    const short* __restrict__ ub,
    const short* __restrict__ Wt, const void* __restrict__ biasv,
    short* __restrict__ xoutb, void* __restrict__ dout, int N,
    const float* __restrict__ flag, int e_force_bf)
{
    constexpr int DIN = L0 ? 160 : 192;
    constexpr int NQ = DIN / 32;
    constexpr int ROWB = DIN * 2;           // 320 (L0) / 384 bytes per row
    __shared__ __align__(16) char Wl[64 * ROWB];   // 20KB / 24KB
    __shared__ __align__(16) char T[4 * 2048];     // 8KB
    const bool isbf = flag[0] != 0.f;
    const bool e_bf = e_force_bf ? true : isbf;
    const int w = threadIdx.x >> 6, j = threadIdx.x & 63;
    const int m16 = j & 15, c8v = j >> 4, c8 = c8v * 8;
    const int rr8 = j >> 3, cc8 = j & 7;
    const int nb = blockIdx.x * 64 + w * 16;

    // stage Wt -> LDS, XOR-swizzled
    for (int i = threadIdx.x; i < DIN * 8; i += 256) {
        int lin = i * 16;
        int row = i / (DIN / 8);
        *(short8*)(Wl + (lin ^ ((row & 7) << 4))) = *(const short8*)(Wt + i * 8);
    }
    __syncthreads();

    char* Tw = T + w * 2048;
    const int wkey = (m16 & 7) << 4;

    int n = nb + m16; if (n > N - 1) n = N - 1;
    int g = batchv[n];

    short8 af[NQ];
    af[0] = ld16s(xin + (size_t)n * 64 + c8);
    af[1] = ld16s(xin + (size_t)n * 64 + 32 + c8);

    // agg-mean for row n, cols c8..c8+7 and 32+c8..+7, straight into fragments
    {
        int st = off[n], c = cntv[n];
        float s0[8] = {0,0,0,0,0,0,0,0}, s1[8] = {0,0,0,0,0,0,0,0};
        int t = 0;
        if (e_bf) {
            const short* ep = (const short*)eout + eoff;
            for (; t + 2 <= c; t += 2) {
                int e0 = csr[st + t], e1 = csr[st + t + 1];
                short8 r0 = ld16s(ep + (size_t)e0 * 64 + c8);
                short8 q0 = ld16s(ep + (size_t)e0 * 64 + 32 + c8);
                short8 r1 = ld16s(ep + (size_t)e1 * 64 + c8);
                short8 q1 = ld16s(ep + (size_t)e1 * 64 + 32 + c8);
                #pragma unroll
                for (int k = 0; k < 8; k++) { s0[k] += bs2f(r0[k]) + bs2f(r1[k]); s1[k] += bs2f(q0[k]) + bs2f(q1[k]); }
            }
            if (t < c) {
                int e0 = csr[st + t];
                short8 r0 = ld16s(ep + (size_t)e0 * 64 + c8);
                short8 q0 = ld16s(ep + (size_t)e0 * 64 + 32 + c8);
                #pragma unroll
                for (int k = 0; k < 8; k++) { s0[k] += bs2f(r0[k]); s1[k] += bs2f(q0[k]); }
            }
        } else {
            const float* ep = (const float*)eout + eoff;
            for (; t < c; t++) {
                int e0 = csr[st + t];
                const float* rp = ep + (size_t)e0 * 64;
                float4 a = *(const float4*)(rp + c8), b = *(const float4*)(rp + c8 + 4);
                float4 x = *(const float4*)(rp + 32 + c8), y = *(const float4*)(rp + 36 + c8);
                s0[0]+=a.x; s0[1]+=a.y; s0[2]+=a.z; s0[3]+=a.w; s0[4]+=b.x; s0[5]+=b.y; s0[6]+=b.z; s0[7]+=b.w;
                s1[0]+=x.x; s1[1]+=x.y; s1[2]+=x.z; s1[3]+=x.w; s1[4]+=y.x; s1[5]+=y.y; s1[6]+=y.z; s1[7]+=y.w;
            }
        }
        float rc = 1.0f / fmaxf((float)c, 1.0f);
        #pragma unroll
        for (int k = 0; k < 8; k++) { af[2][k] = f2bs(s0[k] * rc); af[3][k] = f2bs(s1[k] * rc); }
    }

    if constexpr (L0) {
        af[4] = ld16s(ub + (size_t)g * 32 + c8);          // u 32-wide
    } else {
        af[4] = ld16s(ub + (size_t)g * 64 + c8);
        af[5] = ld16s(ub + (size_t)g * 64 + 32 + c8);
    }

    f32x4 acc[4] = {{0,0,0,0},{0,0,0,0},{0,0,0,0},{0,0,0,0}};
    #pragma unroll
    for (int q = 0; q < NQ; q++) {
        #pragma unroll
        for (int t = 0; t < 4; t++) {
            int lin = (t * 16 + m16) * ROWB + q * 64 + c8v * 16;
            short8 bv = *(const short8*)(Wl + (lin ^ wkey));
            acc[t] = __builtin_amdgcn_mfma_f32_16x16x32_bf16(af[q], bv, acc[t], 0, 0, 0);
        }
    }

    #pragma unroll
    for (int t = 0; t < 4; t++) {
        float bcv = ldv(biasv, t * 16 + m16, isbf);
        #pragma unroll
        for (int r = 0; r < 4; r++) {
            float v = fmaxf(acc[t][r] + bcv, 0.f);
            int rr = c8v * 4 + r;
            int lin = rr * 128 + (t * 16 + m16) * 2;
            *(short*)(Tw + (lin ^ ((rr & 7) << 4))) = f2bs(v);
        }
    }
    #pragma unroll
    for (int i = 0; i < 2; i++) {
        int r = i * 8 + rr8;
        int n2 = nb + r;
        if (n2 < N) {
            short8 row = *(const short8*)(Tw + ((r * 128 + cc8 * 16) ^ ((rr8 & 7) << 4)));
            *(short8*)&xoutb[(size_t)n2 * 64 + cc8 * 8] = row;
            if (FINAL) {
                if (isbf) {
                    *(short8*)((short*)dout + (size_t)n2 * 64 + cc8 * 8) = row;
                } else {
                    float* op = (float*)dout + (size_t)n2 * 64 + cc8 * 8;
                    float4 a, b;
                    a.x=bs2f(row[0]); a.y=bs2f(row[1]); a.z=bs2f(row[2]); a.w=bs2f(row[3]);
                    b.x=bs2f(row[4]); b.y=bs2f(row[5]); b.z=bs2f(row[6]); b.w=bs2f(row[7]);
                    *(float4*)op = a; *(float4*)(op + 4) = b;
                }
            }
        }
    }
}

// ---------------- per-graph pooling: 8 blocks per graph ----------------
__global__ __launch_bounds__(256) void pool_kernel(const int* __restrict__ gstart,
                                                   const short* __restrict__ xb,
                                                   float* __restrict__ gsum) {
    int g = blockIdx.x >> 3, slice = blockIdx.x & 7;
    int st = gstart[g], en = gstart[g + 1];
    int len = en - st;
    int K = (len + 7) >> 3;
    int b0 = st + slice * K;
    int b1 = min(b0 + K, en);
    int rg = threadIdx.x >> 3, cc8 = threadIdx.x & 7;
    float a[8] = {0,0,0,0,0,0,0,0};
    for (int r = b0 + rg; r < b1; r += 32) {
        short8 v = *(const short8*)&xb[(size_t)r * 64 + cc8 * 8];
        #pragma unroll
        for (int k = 0; k < 8; k++) a[k] += bs2f(v[k]);
    }
    __shared__ float sm[32][64];
    #pragma unroll
    for (int k = 0; k < 8; k++) sm[rg][cc8 * 8 + k] = a[k];
    __syncthreads();
    if (threadIdx.x < 64) {
        float s = 0.f;
        #pragma unroll 8
        for (int q = 0; q < 32; q++) s += sm[q][threadIdx.x];
        atomicAdd(&gsum[g * 64 + threadIdx.x], s);
    }
}

// ---------------- Global MLP GEMM: wave per graph ----------------
template<int FU>
__global__ __launch_bounds__(256) void glob_gemm(
    const int* __restrict__ gstart, const float* __restrict__ gsum,
    const float* __restrict__ uin,
    const void* __restrict__ W, const void* __restrict__ biasv,
    float* __restrict__ uoutf, short* __restrict__ uoutb,
    const float* __restrict__ flag)
{
    bool isbf = flag[0] != 0.f;
    const int DIN = 64 + FU;
    __shared__ float s[4][192];
    int w = threadIdx.x >> 6, j = threadIdx.x & 63;
    int g = blockIdx.x * 4 + w;
    int st = gstart[g], en = gstart[g + 1];
    float rc = 1.0f / fmaxf((float)(en - st), 1.0f);
    s[w][j] = gsum[g * 64 + j] * rc;
    if (j < FU) s[w][64 + j] = uin[g * FU + j];
    float acc = ldv(biasv, j, isbf);
    for (int k = 0; k < DIN; k++) acc += s[w][k] * ldv(W, (size_t)k * 64 + j, isbf);
    acc = fmaxf(acc, 0.f);
    uoutf[g * 64 + j] = acc;
    uoutb[g * 64 + j] = f2bs(acc);
}

// ---------------- cast f32 ws -> d_out region ----------------
__global__ __launch_bounds__(256) void cast_out(const float* __restrict__ in, void* __restrict__ out,
                                                size_t out_off, int n, const float* __restrict__ flag) {
    bool isbf = flag[0] != 0.f;
    for (int i = blockIdx.x * 256 + threadIdx.x; i < n; i += gridDim.x * 256)
        stv(out, out_off + i, in[i], isbf);
}

extern "C" void kernel_launch(void* const* d_in, const int* in_sizes, int n_in,
                              void* d_out, int out_size, void* d_ws, size_t ws_size,
                              hipStream_t stream) {
    const void* x_in   = d_in[0];
    const int*  ei     = (const int*)d_in[1];
    const void* e_raw  = d_in[2];
    const void* u_raw  = d_in[3];
    const int*  batchv = (const int*)d_in[4];
    const void *g_node = d_in[5],  *b_node = d_in[6];
    const void *g_edge = d_in[7],  *b_edge = d_in[8];
    const void *g_glob = d_in[9],  *b_glob = d_in[10];
    const void* We[3] = {d_in[11], d_in[17], d_in[23]};
    const void* be[3] = {d_in[12], d_in[18], d_in[24]};
    const void* Wn[3] = {d_in[13], d_in[19], d_in[25]};
    const void* bn[3] = {d_in[14], d_in[20], d_in[26]};
    const void* Wg[3] = {d_in[15], d_in[21], d_in[27]};
    const void* bg[3] = {d_in[16], d_in[22], d_in[28]};

    const int N = in_sizes[0] / 64;   // 30000
    const int E = in_sizes[2] / 32;   // 300000
    const int B = in_sizes[3] / 32;   // 64

    // ---- workspace: contiguous zero-region first (single memset) ----
    float* p = (float*)d_ws;
    float* zbase  = p;
    float* stats  = p; p += 3 * 128;
    int*   cursor = (int*)p; p += 4;
    int*   cnt    = (int*)p; p += N;
    float* gsum0  = p; p += B * 64;
    float* gsum1  = p; p += B * 64;
    float* gsum2  = p; p += B * 64;
    size_t zbytes = (size_t)((char*)p - (char*)zbase);
    float* dflag  = p; p += 4;
    float* uN     = p; p += B * 32;
    float* uA     = p; p += B * 64;
    float* uB     = p; p += B * 64;
    int*   off    = (int*)p; p += N;
    int*   wcur   = (int*)p; p += N;
    int*   gstart = (int*)p; p += 72;
    int*   csr    = (int*)p; p += E;
    short* xb0    = (short*)p; p += (size_t)N * 32;
    short* xb1    = (short*)p; p += (size_t)N * 32;
    short* ubN    = (short*)p; p += B * 16;
    short* ubA    = (short*)p; p += B * 32;
    short* ubB    = (short*)p; p += B * 32;
    short* WtAll  = (short*)p; p += 79872 / 2;
    const short* WtE0 = WtAll;
    const short* WtE1 = WtAll + 12288;
    const short* WtE2 = WtAll + 28672;
    const short* WtN0 = WtAll + 45056;
    const short* WtN1 = WtAll + 55296;
    const short* WtN2 = WtAll + 67584;

    // bf16 intermediate-e buffer (E x 64 shorts), if workspace has room
    short* eb16 = nullptr;
    {
        size_t used = (size_t)((char*)p - (char*)d_ws);
        used = (used + 15) & ~(size_t)15;
        size_t need = used + (size_t)E * 64 * sizeof(short);
        if (ws_size >= need) eb16 = (short*)((char*)d_ws + used);
    }

    const size_t EOFF = (size_t)N * 64;
    const size_t UOFF = EOFF + (size_t)E * 64;

    hipMemsetAsync(zbase, 0, zbytes, stream);

    detect_dtype<<<1, 256, 0, stream>>>((const unsigned short*)x_in, dflag);

    bn_stats<64><<<256, 256, 0, stream>>>(x_in, N, stats, dflag);
    bn_stats<32><<<512, 256, 0, stream>>>(e_raw, E, stats + 128, dflag);
    bn_stats<32><<<8,   256, 0, stream>>>(u_raw, B, stats + 256, dflag);
    bn_apply_x<<<512, 256, 0, stream>>>(x_in, xb0, stats, N, g_node, b_node, dflag);
    bn_apply_u<<<8,   256, 0, stream>>>(u_raw, uN, ubN, stats + 256, B, g_glob, b_glob, dflag);
    count_kernel<<<512, 256, 0, stream>>>(ei, cnt, E);
    csr_offsets<<<(N + 255) / 256, 256, 0, stream>>>(cnt, off, wcur, cursor, N, batchv, gstart, B);
    csr_fill<<<512, 256, 0, stream>>>(ei, wcur, csr, E);
    transpose_w<<<48, 256, 0, stream>>>(We[0], We[1], We[2], Wn[0], Wn[1], Wn[2], WtAll, dflag);

    const int NG = (N + 63) / 64;   // 469
    const int NT = (E + 63) / 64;   // 4688 tiles
    const int EG0 = NT < 1280 ? NT : 1280;   // L0: 32KB LDS -> 5 blocks/CU
    const int EG  = NT < 1024 ? NT : 1024;   // L1/2: 40KB LDS -> 4 blocks/CU

    if (eb16) {
        // ---- bf16 intermediate-e flow ----
        // layer 0
        edge_mfma<true><<<EG0, 256, 0, stream>>>(
            ei, batchv, xb0, e_raw, 0, stats + 128, g_edge, b_edge,
            ubN, WtE0, be[0], eb16, 0, E, dflag, 0, 1, nullptr);
        node_fused<true, false><<<NG, 256, 0, stream>>>(
            batchv, xb0, off, csr, cnt, eb16, 0, ubN, WtN0, bn[0], xb1, nullptr, N, dflag, 1);
        pool_kernel<<<B * 8, 256, 0, stream>>>(gstart, xb1, gsum0);
        glob_gemm<32><<<B / 4, 256, 0, stream>>>(gstart, gsum0, uN, Wg[0], bg[0], uA, ubA, dflag);

        // layer 1 (e in-place bf16: wave-private row windows, safe)
        edge_mfma<false><<<EG, 256, 0, stream>>>(
            ei, batchv, xb1, eb16, 0, nullptr, nullptr, nullptr,
            ubA, WtE1, be[1], eb16, 0, E, dflag, 1, 1, nullptr);
        node_fused<false, false><<<NG, 256, 0, stream>>>(
            batchv, xb1, off, csr, cnt, eb16, 0, ubA, WtN1, bn[1], xb0, nullptr, N, dflag, 1);
        pool_kernel<<<B * 8, 256, 0, stream>>>(gstart, xb0, gsum1);
        glob_gemm<64><<<B / 4, 256, 0, stream>>>(gstart, gsum1, uA, Wg[1], bg[1], uB, ubB, dflag);

        // layer 2: final e -> d_out (input dtype) + bf16 copy for node gather
        edge_mfma<false><<<EG, 256, 0, stream>>>(
            ei, batchv, xb0, eb16, 0, nullptr, nullptr, nullptr,
            ubB, WtE2, be[2], d_out, EOFF, E, dflag, 1, 0, eb16);
        node_fused<false, true><<<NG, 256, 0, stream>>>(
            batchv, xb0, off, csr, cnt, eb16, 0, ubB, WtN2, bn[2], xb1, d_out, N, dflag, 1);
        pool_kernel<<<B * 8, 256, 0, stream>>>(gstart, xb1, gsum2);
        glob_gemm<64><<<B / 4, 256, 0, stream>>>(gstart, gsum2, uB, Wg[2], bg[2], uA, ubA, dflag);
    } else {
        // ---- fallback: original flow, e intermediate in d_out (input dtype) ----
        edge_mfma<true><<<EG0, 256, 0, stream>>>(
            ei, batchv, xb0, e_raw, 0, stats + 128, g_edge, b_edge,
            ubN, WtE0, be[0], d_out, EOFF, E, dflag, 0, 0, nullptr);
        node_fused<true, false><<<NG, 256, 0, stream>>>(
            batchv, xb0, off, csr, cnt, d_out, EOFF, ubN, WtN0, bn[0], xb1, nullptr, N, dflag, 0);
        pool_kernel<<<B * 8, 256, 0, stream>>>(gstart, xb1, gsum0);
        glob_gemm<32><<<B / 4, 256, 0, stream>>>(gstart, gsum0, uN, Wg[0], bg[0], uA, ubA, dflag);

        edge_mfma<false><<<EG, 256, 0, stream>>>(
            ei, batchv, xb1, d_out, EOFF, nullptr, nullptr, nullptr,
            ubA, WtE1, be[1], d_out, EOFF, E, dflag, 0, 0, nullptr);
        node_fused<false, false><<<NG, 256, 0, stream>>>(
            batchv, xb1, off, csr, cnt, d_out, EOFF, ubA, WtN1, bn[1], xb0, nullptr, N, dflag, 0);
        pool_kernel<<<B * 8, 256, 0, stream>>>(gstart, xb0, gsum1);
        glob_gemm<64><<<B / 4, 256, 0, stream>>>(gstart, gsum1, uA, Wg[1], bg[1], uB, ubB, dflag);

        edge_mfma<false><<<EG, 256, 0, stream>>>(
            ei, batchv, xb0, d_out, EOFF, nullptr, nullptr, nullptr,
            ubB, WtE2, be[2], d_out, EOFF, E, dflag, 0, 0, nullptr);
        node_fused<false, true><<<NG, 256, 0, stream>>>(
            batchv, xb0, off, csr, cnt, d_out, EOFF, ubB, WtN2, bn[2], xb1, d_out, N, dflag, 0);
        pool_kernel<<<B * 8, 256, 0, stream>>>(gstart, xb1, gsum2);
        glob_gemm<64><<<B / 4, 256, 0, stream>>>(gstart, gsum2, uB, Wg[2], bg[2], uA, ubA, dflag);
    }

    // ---- u output ----
    cast_out<<<16, 256, 0, stream>>>(uA, d_out, UOFF, B * 64, dflag);
}

// Round 6
// 470.033 us; speedup vs baseline: 1.7976x; 1.0238x over previous
//
#include <hip/hip_runtime.h>
#include <hip/hip_bf16.h>

#define EPS 1e-5f
typedef __hip_bfloat16 bf16;
typedef __attribute__((ext_vector_type(8))) short  short8;
typedef __attribute__((ext_vector_type(4))) float  f32x4;

__device__ __forceinline__ float b2f(bf16 v) { return __bfloat162float(v); }
__device__ __forceinline__ float bs2f(short s) { bf16 b = *reinterpret_cast<bf16*>(&s); return b2f(b); }
__device__ __forceinline__ float ldv(const void* p, size_t i, bool bf) {
    return bf ? b2f(((const bf16*)p)[i]) : ((const float*)p)[i];
}
__device__ __forceinline__ void stv(void* p, size_t i, float v, bool bf) {
    if (bf) ((bf16*)p)[i] = __float2bfloat16(v);
    else    ((float*)p)[i] = v;
}
__device__ __forceinline__ short f2bs(float v) {
    bf16 b = __float2bfloat16(v);
    return *reinterpret_cast<short*>(&b);
}
__device__ __forceinline__ short8 ld16s(const short* p) { return *(const short8*)p; }

// ---------------- dtype detector ----------------
__global__ void detect_dtype(const unsigned short* __restrict__ xs, float* __restrict__ flag) {
    __shared__ int cnt;
    if (threadIdx.x == 0) cnt = 0;
    __syncthreads();
    unsigned short u = xs[threadIdx.x];
    int e = (u >> 7) & 0xFF;
    int sane = (u == 0 || (e >= 110 && e <= 140)) ? 1 : 0;
    atomicAdd(&cnt, sane);
    __syncthreads();
    if (threadIdx.x == 0) flag[0] = (cnt >= 230) ? 1.0f : 0.0f;
}

// ---------------- BatchNorm stats ----------------
template<int C>
__global__ __launch_bounds__(256) void bn_stats(const void* __restrict__ in, int R,
                                                float* __restrict__ stats, const float* __restrict__ flag) {
    bool isbf = flag[0] != 0.f;
    const int RG = 256 / C;
    int c = threadIdx.x % C, rg = threadIdx.x / C;
    float s = 0.f, s2 = 0.f;
    if (isbf) {
        const bf16* ip = (const bf16*)in;
        for (int r = blockIdx.x * RG + rg; r < R; r += gridDim.x * RG) {
            float v = b2f(ip[(size_t)r * C + c]); s += v; s2 += v * v;
        }
    } else {
        const float* ip = (const float*)in;
        for (int r = blockIdx.x * RG + rg; r < R; r += gridDim.x * RG) {
            float v = ip[(size_t)r * C + c]; s += v; s2 += v * v;
        }
    }
    __shared__ float sm[2][256];
    sm[0][threadIdx.x] = s; sm[1][threadIdx.x] = s2;
    __syncthreads();
    if (threadIdx.x < C) {
        float ts = 0.f, t2 = 0.f;
        for (int g = 0; g < RG; g++) { ts += sm[0][g * C + c]; t2 += sm[1][g * C + c]; }
        atomicAdd(&stats[c], ts);
        atomicAdd(&stats[C + c], t2);
    }
}

// ---------------- BN apply: x -> bf16 internal ----------------
__global__ __launch_bounds__(256) void bn_apply_x(const void* __restrict__ in, short* __restrict__ out,
                                                  const float* __restrict__ stats, int R,
                                                  const void* __restrict__ gamma, const void* __restrict__ beta,
                                                  const float* __restrict__ flag) {
    bool isbf = flag[0] != 0.f;
    int total = R * 64;
    for (int i = blockIdx.x * 256 + threadIdx.x; i < total; i += gridDim.x * 256) {
        int c = i & 63;
        float mean = stats[c] / (float)R;
        float var = stats[64 + c] / (float)R - mean * mean;
        float inv = rsqrtf(var + EPS);
        out[i] = f2bs(ldv(gamma, c, isbf) * (ldv(in, i, isbf) - mean) * inv + ldv(beta, c, isbf));
    }
}

// ---------------- BN apply: u -> f32 + bf16 tables ----------------
__global__ __launch_bounds__(256) void bn_apply_u(const void* __restrict__ in, float* __restrict__ outf,
                                                  short* __restrict__ outb,
                                                  const float* __restrict__ stats, int R,
                                                  const void* __restrict__ gamma, const void* __restrict__ beta,
                                                  const float* __restrict__ flag) {
    bool isbf = flag[0] != 0.f;
    int total = R * 32;
    for (int i = blockIdx.x * 256 + threadIdx.x; i < total; i += gridDim.x * 256) {
        int c = i & 31;
        float mean = stats[c] / (float)R;
        float var = stats[32 + c] / (float)R - mean * mean;
        float inv = rsqrtf(var + EPS);
        float v = ldv(gamma, c, isbf) * (ldv(in, i, isbf) - mean) * inv + ldv(beta, c, isbf);
        outf[i] = v; outb[i] = f2bs(v);
    }
}

// ---------------- per-dst edge counts ----------------
__global__ __launch_bounds__(256) void count_kernel(const int* __restrict__ ei, int* __restrict__ cnt, int E) {
    int stride = gridDim.x * 256;
    for (int t = blockIdx.x * 256 + threadIdx.x; t < E; t += stride) atomicAdd(&cnt[ei[E + t]], 1);
}

// ---------------- CSR offsets + per-graph ranges (merged) ----------------
__global__ __launch_bounds__(256) void csr_offsets(const int* __restrict__ cnt, int* __restrict__ off,
                                                   int* __restrict__ wcur, int* __restrict__ cursor, int N,
                                                   const int* __restrict__ batch, int* __restrict__ gstart, int B) {
    int n = blockIdx.x * 256 + threadIdx.x;
    if (n < N) {
        int o = atomicAdd(cursor, cnt[n]);
        off[n] = o; wcur[n] = o;
    }
    if (blockIdx.x == 0 && threadIdx.x <= B) {
        int t = threadIdx.x;
        int lo = 0, hi = N;
        while (lo < hi) { int mid = (lo + hi) >> 1; if (batch[mid] < t) lo = mid + 1; else hi = mid; }
        gstart[t] = lo;
    }
}

__global__ __launch_bounds__(256) void csr_fill(const int* __restrict__ ei, int* __restrict__ wcur,
                                                int* __restrict__ csr, int E) {
    int stride = gridDim.x * 256;
    for (int t = blockIdx.x * 256 + threadIdx.x; t < E; t += stride) {
        int d = ei[E + t];
        int pos = atomicAdd(&wcur[d], 1);
        csr[pos] = t;
    }
}

// ---------------- permuted src/dst arrays (CSR order) ----------------
__global__ __launch_bounds__(256) void perm_build(const int* __restrict__ ei, const int* __restrict__ csr,
                                                  int* __restrict__ sp, int* __restrict__ dp, int E) {
    int stride = gridDim.x * 256;
    for (int t = blockIdx.x * 256 + threadIdx.x; t < E; t += stride) {
        int e0 = csr[t];
        sp[t] = ei[e0];
        dp[t] = ei[E + e0];
    }
}

// ---------------- W transpose prep ----------------
__global__ __launch_bounds__(256) void transpose_w(
    const void* __restrict__ W0, const void* __restrict__ W1, const void* __restrict__ W2,
    const void* __restrict__ W3, const void* __restrict__ W4, const void* __restrict__ W5,
    short* __restrict__ out, const float* __restrict__ flag)
{
    bool isbf = flag[0] != 0.f;
    const void* Ws[6] = {W0, W1, W2, W3, W4, W5};
    const int   din[6] = {192, 256, 256, 160, 192, 192};
    int mtx = blockIdx.x >> 3;
    int off = 0;
    for (int i = 0; i < mtx; i++) off += 64 * din[i];
    int d = din[mtx];
    const void* W = Ws[mtx];
    for (int i = (blockIdx.x & 7) * 256 + threadIdx.x; i < 64 * d; i += 8 * 256) {
        int n = i / d, k = i % d;
        out[off + n * d + k] = f2bs(ldv(W, (size_t)k * 64 + n, isbf));
    }
}

// ---------------- Edge MLP via MFMA: LDS-staged swizzled Wt + persistent tiles, CSR-position ordering ----------------
// Rows are CSR positions t. sp/dp give src/dst per position (coalesced).
// csrv (if non-null) maps position -> original edge id; used for L0's raw-e gather and the
// final-layer d_out scatter (eout_orig=1). eout2 (bf16 copy) always position-ordered.
template<bool L0>
__global__ __launch_bounds__(256) void edge_mfma(
    const int* __restrict__ sp, const int* __restrict__ dp,
    const int* __restrict__ csrv,
    const int* __restrict__ batchv,
    const short* __restrict__ xb,
    const void* __restrict__ ein, size_t ein_off,
    const float* __restrict__ estats, const void* __restrict__ egamma, const void* __restrict__ ebeta,
    const short* __restrict__ ub,
    const short* __restrict__ Wt, const void* __restrict__ biasv,
    void* __restrict__ eout, size_t eout_off,
    int E, const float* __restrict__ flag,
    int ein_force_bf, int eout_force_bf, int eout_orig, short* __restrict__ eout2)
{
    constexpr int DIN = L0 ? 192 : 256;
    constexpr int NQ = DIN / 32;
    constexpr int ROWB = DIN * 2;           // bytes per Wt row
    __shared__ __align__(16) char Wl[64 * ROWB];   // 24KB (L0) / 32KB
    __shared__ __align__(16) char T[4 * 2048];     // swizzled epilogue transpose, 8KB
    const bool isbf = flag[0] != 0.f;
    const bool ein_bf = ein_force_bf ? true : isbf;
    const bool eout_bf = eout_force_bf ? true : isbf;
    const int w = threadIdx.x >> 6, j = threadIdx.x & 63;
    const int m16 = j & 15, c8v = j >> 4, c8 = c8v * 8;
    const int rr8 = j >> 3, cc8 = j & 7;

    // stage Wt -> LDS, XOR-swizzled (byte ^= (row&7)<<4)
    for (int i = threadIdx.x; i < DIN * 8; i += 256) {
        int lin = i * 16;
        int row = i / (DIN / 8);
        *(short8*)(Wl + (lin ^ ((row & 7) << 4))) = *(const short8*)(Wt + i * 8);
    }
    __syncthreads();

    char* Tw = T + w * 2048;
    const int wkey = (m16 & 7) << 4;

    // loop-invariant BN constants (L0) and bias
    float sc[8], sh[8];
    if constexpr (L0) {
        #pragma unroll
        for (int k = 0; k < 8; k++) {
            int col = c8 + k;
            float m = estats[col] / (float)E;
            float iv = rsqrtf(estats[32 + col] / (float)E - m * m + EPS);
            sc[k] = ldv(egamma, col, isbf) * iv;
            sh[k] = ldv(ebeta, col, isbf) - m * sc[k];
        }
    }
    float bc[4];
    #pragma unroll
    for (int t = 0; t < 4; t++) bc[t] = ldv(biasv, t * 16 + m16, isbf);

    const int ntiles = (E + 63) >> 6;
    const int gs = gridDim.x;
    int tile = blockIdx.x;
    if (tile < ntiles) {
        // idx prefetch state: few VGPRs only (lesson from R4 spill regression)
        int ec = tile * 64 + w * 16 + m16; if (ec > E - 1) ec = E - 1;
        int s = sp[ec], d = dp[ec];
        int eo = ec;
        if constexpr (L0) { if (csrv) eo = csrv[ec]; }
        for (; tile < ntiles; tile += gs) {
            const int ecC = ec, sC = s, dC = d, eoC = eo;
            const int tn = tile + gs;
            if (tn < ntiles) {          // issue next-tile index loads now; consumed next iteration
                int e2 = tn * 64 + w * 16 + m16; if (e2 > E - 1) e2 = E - 1;
                ec = e2; s = sp[e2]; d = dp[e2];
                if constexpr (L0) { if (csrv) eo = csrv[e2]; }
            }
            int g = batchv[sC];

            short8 af[NQ];
            af[0] = ld16s(xb + (size_t)sC * 64 + c8);
            af[1] = ld16s(xb + (size_t)sC * 64 + 32 + c8);
            af[2] = ld16s(xb + (size_t)dC * 64 + c8);
            af[3] = ld16s(xb + (size_t)dC * 64 + 32 + c8);
            if constexpr (L0) {
                float ev[8];
                if (isbf) {
                    short8 r = ld16s((const short*)ein + (size_t)eoC * 32 + c8);
                    #pragma unroll
                    for (int k = 0; k < 8; k++) ev[k] = bs2f(r[k]);
                } else {
                    const float* ef = (const float*)ein + (size_t)eoC * 32 + c8;
                    float4 a = *(const float4*)ef, b = *(const float4*)(ef + 4);
                    ev[0]=a.x; ev[1]=a.y; ev[2]=a.z; ev[3]=a.w; ev[4]=b.x; ev[5]=b.y; ev[6]=b.z; ev[7]=b.w;
                }
                #pragma unroll
                for (int k = 0; k < 8; k++) af[4][k] = f2bs(ev[k] * sc[k] + sh[k]);
                af[5] = ld16s(ub + (size_t)g * 32 + c8);          // u is 32-wide in layer 0
            } else {
                if (ein_bf) {
                    af[4] = ld16s((const short*)ein + ein_off + (size_t)ecC * 64 + c8);
                    af[5] = ld16s((const short*)ein + ein_off + (size_t)ecC * 64 + 32 + c8);
                } else {
                    const float* ef = (const float*)ein + ein_off + (size_t)ecC * 64;
                    float4 a = *(const float4*)(ef + c8), b = *(const float4*)(ef + c8 + 4);
                    af[4][0]=f2bs(a.x); af[4][1]=f2bs(a.y); af[4][2]=f2bs(a.z); af[4][3]=f2bs(a.w);
                    af[4][4]=f2bs(b.x); af[4][5]=f2bs(b.y); af[4][6]=f2bs(b.z); af[4][7]=f2bs(b.w);
                    a = *(const float4*)(ef + 32 + c8); b = *(const float4*)(ef + 36 + c8);
                    af[5][0]=f2bs(a.x); af[5][1]=f2bs(a.y); af[5][2]=f2bs(a.z); af[5][3]=f2bs(a.w);
                    af[5][4]=f2bs(b.x); af[5][5]=f2bs(b.y); af[5][6]=f2bs(b.z); af[5][7]=f2bs(b.w);
                }
                af[6] = ld16s(ub + (size_t)g * 64 + c8);
                af[7] = ld16s(ub + (size_t)g * 64 + 32 + c8);
            }

            f32x4 acc[4] = {{0,0,0,0},{0,0,0,0},{0,0,0,0},{0,0,0,0}};
            #pragma unroll
            for (int q = 0; q < NQ; q++) {
                #pragma unroll
                for (int t = 0; t < 4; t++) {
                    int lin = (t * 16 + m16) * ROWB + q * 64 + c8v * 16;
                    short8 bv = *(const short8*)(Wl + (lin ^ wkey));
                    acc[t] = __builtin_amdgcn_mfma_f32_16x16x32_bf16(af[q], bv, acc[t], 0, 0, 0);
                }
            }

            // epilogue: wave-private swizzled LDS transpose -> coalesced row stores
            const int we = tile * 64 + w * 16;
            #pragma unroll
            for (int t = 0; t < 4; t++) {
                #pragma unroll
                for (int r = 0; r < 4; r++) {
                    float v = fmaxf(acc[t][r] + bc[t], 0.f);
                    int rr = c8v * 4 + r;
                    int lin = rr * 128 + (t * 16 + m16) * 2;
                    *(short*)(Tw + (lin ^ ((rr & 7) << 4))) = f2bs(v);
                }
            }
            #pragma unroll
            for (int i = 0; i < 2; i++) {
                int r = i * 8 + rr8;
                int e2 = we + r;
                if (e2 < E) {
                    short8 row = *(const short8*)(Tw + ((r * 128 + cc8 * 16) ^ ((rr8 & 7) << 4)));
                    int rowIdx = (eout_orig && csrv) ? csrv[e2] : e2;
                    if (eout_bf) {
                        *(short8*)((short*)eout + eout_off + (size_t)rowIdx * 64 + cc8 * 8) = row;
                    } else {
                        float* op = (float*)eout + eout_off + (size_t)rowIdx * 64 + cc8 * 8;
                        float4 a, b;
                        a.x=bs2f(row[0]); a.y=bs2f(row[1]); a.z=bs2f(row[2]); a.w=bs2f(row[3]);
                        b.x=bs2f(row[4]); b.y=bs2f(row[5]); b.z=bs2f(row[6]); b.w=bs2f(row[7]);
                        *(float4*)op = a; *(float4*)(op + 4) = b;
                    }
                    if (eout2) {
                        *(short8*)(eout2 + (size_t)e2 * 64 + cc8 * 8) = row;
                    }
                }
            }
        }
    }
}

// ---------------- Node MLP: LDS-staged swizzled Wt + contiguous (CSR-position) agg-mean ----------------
template<bool L0, bool FINAL>
__global__ __launch_bounds__(256) void node_fused(
    const int* __restrict__ batchv, const short* __restrict__ xin,
    const int* __restrict__ off, const int* __restrict__ csr, const int* __restrict__ cntv,
    const void* __restrict__ eout, size_t eoff,
    const short* __restrict__ ub,
    const short* __restrict__ Wt, const void* __restrict__ biasv,
    short* __restrict__ xoutb, void* __restrict__ dout, int N,
    const float* __restrict__ flag, int e_force_bf, int contig)
{
    constexpr int DIN = L0 ? 160 : 192;
    constexpr int NQ = DIN / 32;
    constexpr int ROWB = DIN * 2;           // 320 (L0) / 384 bytes per row
    __shared__ __align__(16) char Wl[64 * ROWB];   // 20KB / 24KB
    __shared__ __align__(16) char T[4 * 2048];     // 8KB
    const bool isbf = flag[0] != 0.f;
    const bool e_bf = e_force_bf ? true : isbf;
    const int w = threadIdx.x >> 6, j = threadIdx.x & 63;
    const int m16 = j & 15, c8v = j >> 4, c8 = c8v * 8;
    const int rr8 = j >> 3, cc8 = j & 7;
    const int nb = blockIdx.x * 64 + w * 16;

    // stage Wt -> LDS, XOR-swizzled
    for (int i = threadIdx.x; i < DIN * 8; i += 256) {
        int lin = i * 16;
        int row = i / (DIN / 8);
        *(short8*)(Wl + (lin ^ ((row & 7) << 4))) = *(const short8*)(Wt + i * 8);
    }
    __syncthreads();

    char* Tw = T + w * 2048;
    const int wkey = (m16 & 7) << 4;

    int n = nb + m16; if (n > N - 1) n = N - 1;
    int g = batchv[n];

    short8 af[NQ];
    af[0] = ld16s(xin + (size_t)n * 64 + c8);
    af[1] = ld16s(xin + (size_t)n * 64 + 32 + c8);

    // agg-mean for row n, cols c8..c8+7 and 32+c8..+7, straight into fragments
    {
        int st = off[n], c = cntv[n];
        float s0[8] = {0,0,0,0,0,0,0,0}, s1[8] = {0,0,0,0,0,0,0,0};
        if (e_bf) {
            const short* ep = (const short*)eout + eoff;
            if (contig) {
                // e rows stored in CSR position order: pure streaming over st..st+c
                const short* base = ep + (size_t)st * 64;
                int t = 0;
                for (; t + 2 <= c; t += 2) {
                    short8 r0 = ld16s(base + (size_t)t * 64 + c8);
                    short8 q0 = ld16s(base + (size_t)t * 64 + 32 + c8);
                    short8 r1 = ld16s(base + (size_t)(t + 1) * 64 + c8);
                    short8 q1 = ld16s(base + (size_t)(t + 1) * 64 + 32 + c8);
                    #pragma unroll
                    for (int k = 0; k < 8; k++) { s0[k] += bs2f(r0[k]) + bs2f(r1[k]); s1[k] += bs2f(q0[k]) + bs2f(q1[k]); }
                }
                if (t < c) {
                    short8 r0 = ld16s(base + (size_t)t * 64 + c8);
                    short8 q0 = ld16s(base + (size_t)t * 64 + 32 + c8);
                    #pragma unroll
                    for (int k = 0; k < 8; k++) { s0[k] += bs2f(r0[k]); s1[k] += bs2f(q0[k]); }
                }
            } else {
                int t = 0;
                for (; t + 2 <= c; t += 2) {
                    int e0 = csr[st + t], e1 = csr[st + t + 1];
                    short8 r0 = ld16s(ep + (size_t)e0 * 64 + c8);
                    short8 q0 = ld16s(ep + (size_t)e0 * 64 + 32 + c8);
                    short8 r1 = ld16s(ep + (size_t)e1 * 64 + c8);
                    short8 q1 = ld16s(ep + (size_t)e1 * 64 + 32 + c8);
                    #pragma unroll
                    for (int k = 0; k < 8; k++) { s0[k] += bs2f(r0[k]) + bs2f(r1[k]); s1[k] += bs2f(q0[k]) + bs2f(q1[k]); }
                }
                if (t < c) {
                    int e0 = csr[st + t];
                    short8 r0 = ld16s(ep + (size_t)e0 * 64 + c8);
                    short8 q0 = ld16s(ep + (size_t)e0 * 64 + 32 + c8);
                    #pragma unroll
                    for (int k = 0; k < 8; k++) { s0[k] += bs2f(r0[k]); s1[k] += bs2f(q0[k]); }
                }
            }
        } else {
            const float* ep = (const float*)eout + eoff;
            for (int t = 0; t < c; t++) {
                int e0 = csr[st + t];
                const float* rp = ep + (size_t)e0 * 64;
                float4 a = *(const float4*)(rp + c8), b = *(const float4*)(rp + c8 + 4);
                float4 x = *(const float4*)(rp + 32 + c8), y = *(const float4*)(rp + 36 + c8);
                s0[0]+=a.x; s0[1]+=a.y; s0[2]+=a.z; s0[3]+=a.w; s0[4]+=b.x; s0[5]+=b.y; s0[6]+=b.z; s0[7]+=b.w;
                s1[0]+=x.x; s1[1]+=x.y; s1[2]+=x.z; s1[3]+=x.w; s1[4]+=y.x; s1[5]+=y.y; s1[6]+=y.z; s1[7]+=y.w;
            }
        }
        float rc = 1.0f / fmaxf((float)c, 1.0f);
        #pragma unroll
        for (int k = 0; k < 8; k++) { af[2][k] = f2bs(s0[k] * rc); af[3][k] = f2bs(s1[k] * rc); }
    }

    if constexpr (L0) {
        af[4] = ld16s(ub + (size_t)g * 32 + c8);          // u 32-wide
    } else {
        af[4] = ld16s(ub + (size_t)g * 64 + c8);
        af[5] = ld16s(ub + (size_t)g * 64 + 32 + c8);
    }

    f32x4 acc[4] = {{0,0,0,0},{0,0,0,0},{0,0,0,0},{0,0,0,0}};
    #pragma unroll
    for (int q = 0; q < NQ; q++) {
        #pragma unroll
        for (int t = 0; t < 4; t++) {
            int lin = (t * 16 + m16) * ROWB + q * 64 + c8v * 16;
            short8 bv = *(const short8*)(Wl + (lin ^ wkey));
            acc[t] = __builtin_amdgcn_mfma_f32_16x16x32_bf16(af[q], bv, acc[t], 0, 0, 0);
        }
    }

    #pragma unroll
    for (int t = 0; t < 4; t++) {
        float bcv = ldv(biasv, t * 16 + m16, isbf);
        #pragma unroll
        for (int r = 0; r < 4; r++) {
            float v = fmaxf(acc[t][r] + bcv, 0.f);
            int rr = c8v * 4 + r;
            int lin = rr * 128 + (t * 16 + m16) * 2;
            *(short*)(Tw + (lin ^ ((rr & 7) << 4))) = f2bs(v);
        }
    }
    #pragma unroll
    for (int i = 0; i < 2; i++) {
        int r = i * 8 + rr8;
        int n2 = nb + r;
        if (n2 < N) {
            short8 row = *(const short8*)(Tw + ((r * 128 + cc8 * 16) ^ ((rr8 & 7) << 4)));
            *(short8*)&xoutb[(size_t)n2 * 64 + cc8 * 8] = row;
            if (FINAL) {
                if (isbf) {
                    *(short8*)((short*)dout + (size_t)n2 * 64 + cc8 * 8) = row;
                } else {
                    float* op = (float*)dout + (size_t)n2 * 64 + cc8 * 8;
                    float4 a, b;
                    a.x=bs2f(row[0]); a.y=bs2f(row[1]); a.z=bs2f(row[2]); a.w=bs2f(row[3]);
                    b.x=bs2f(row[4]); b.y=bs2f(row[5]); b.z=bs2f(row[6]); b.w=bs2f(row[7]);
                    *(float4*)op = a; *(float4*)(op + 4) = b;
                }
            }
        }
    }
}

// ---------------- per-graph pooling: 8 blocks per graph ----------------
__global__ __launch_bounds__(256) void pool_kernel(const int* __restrict__ gstart,
                                                   const short* __restrict__ xb,
                                                   float* __restrict__ gsum) {
    int g = blockIdx.x >> 3, slice = blockIdx.x & 7;
    int st = gstart[g], en = gstart[g + 1];
    int len = en - st;
    int K = (len + 7) >> 3;
    int b0 = st + slice * K;
    int b1 = min(b0 + K, en);
    int rg = threadIdx.x >> 3, cc8 = threadIdx.x & 7;
    float a[8] = {0,0,0,0,0,0,0,0};
    for (int r = b0 + rg; r < b1; r += 32) {
        short8 v = *(const short8*)&xb[(size_t)r * 64 + cc8 * 8];
        #pragma unroll
        for (int k = 0; k < 8; k++) a[k] += bs2f(v[k]);
    }
    __shared__ float sm[32][64];
    #pragma unroll
    for (int k = 0; k < 8; k++) sm[rg][cc8 * 8 + k] = a[k];
    __syncthreads();
    if (threadIdx.x < 64) {
        float s = 0.f;
        #pragma unroll 8
        for (int q = 0; q < 32; q++) s += sm[q][threadIdx.x];
        atomicAdd(&gsum[g * 64 + threadIdx.x], s);
    }
}

// ---------------- Global MLP GEMM: wave per graph ----------------
template<int FU>
__global__ __launch_bounds__(256) void glob_gemm(
    const int* __restrict__ gstart, const float* __restrict__ gsum,
    const float* __restrict__ uin,
    const void* __restrict__ W, const void* __restrict__ biasv,
    float* __restrict__ uoutf, short* __restrict__ uoutb,
    const float* __restrict__ flag)
{
    bool isbf = flag[0] != 0.f;
    const int DIN = 64 + FU;
    __shared__ float s[4][192];
    int w = threadIdx.x >> 6, j = threadIdx.x & 63;
    int g = blockIdx.x * 4 + w;
    int st = gstart[g], en = gstart[g + 1];
    float rc = 1.0f / fmaxf((float)(en - st), 1.0f);
    s[w][j] = gsum[g * 64 + j] * rc;
    if (j < FU) s[w][64 + j] = uin[g * FU + j];
    float acc = ldv(biasv, j, isbf);
    for (int k = 0; k < DIN; k++) acc += s[w][k] * ldv(W, (size_t)k * 64 + j, isbf);
    acc = fmaxf(acc, 0.f);
    uoutf[g * 64 + j] = acc;
    uoutb[g * 64 + j] = f2bs(acc);
}

// ---------------- cast f32 ws -> d_out region ----------------
__global__ __launch_bounds__(256) void cast_out(const float* __restrict__ in, void* __restrict__ out,
                                                size_t out_off, int n, const float* __restrict__ flag) {
    bool isbf = flag[0] != 0.f;
    for (int i = blockIdx.x * 256 + threadIdx.x; i < n; i += gridDim.x * 256)
        stv(out, out_off + i, in[i], isbf);
}

extern "C" void kernel_launch(void* const* d_in, const int* in_sizes, int n_in,
                              void* d_out, int out_size, void* d_ws, size_t ws_size,
                              hipStream_t stream) {
    const void* x_in   = d_in[0];
    const int*  ei     = (const int*)d_in[1];
    const void* e_raw  = d_in[2];
    const void* u_raw  = d_in[3];
    const int*  batchv = (const int*)d_in[4];
    const void *g_node = d_in[5],  *b_node = d_in[6];
    const void *g_edge = d_in[7],  *b_edge = d_in[8];
    const void *g_glob = d_in[9],  *b_glob = d_in[10];
    const void* We[3] = {d_in[11], d_in[17], d_in[23]};
    const void* be[3] = {d_in[12], d_in[18], d_in[24]};
    const void* Wn[3] = {d_in[13], d_in[19], d_in[25]};
    const void* bn[3] = {d_in[14], d_in[20], d_in[26]};
    const void* Wg[3] = {d_in[15], d_in[21], d_in[27]};
    const void* bg[3] = {d_in[16], d_in[22], d_in[28]};

    const int N = in_sizes[0] / 64;   // 30000
    const int E = in_sizes[2] / 32;   // 300000
    const int B = in_sizes[3] / 32;   // 64

    // ---- workspace: contiguous zero-region first (single memset) ----
    float* p = (float*)d_ws;
    float* zbase  = p;
    float* stats  = p; p += 3 * 128;
    int*   cursor = (int*)p; p += 4;
    int*   cnt    = (int*)p; p += N;
    float* gsum0  = p; p += B * 64;
    float* gsum1  = p; p += B * 64;
    float* gsum2  = p; p += B * 64;
    size_t zbytes = (size_t)((char*)p - (char*)zbase);
    float* dflag  = p; p += 4;
    float* uN     = p; p += B * 32;
    float* uA     = p; p += B * 64;
    float* uB     = p; p += B * 64;
    int*   off    = (int*)p; p += N;
    int*   wcur   = (int*)p; p += N;
    int*   gstart = (int*)p; p += 72;
    int*   csr    = (int*)p; p += E;
    int*   sp     = (int*)p; p += E;
    int*   dp     = (int*)p; p += E;
    short* xb0    = (short*)p; p += (size_t)N * 32;
    short* xb1    = (short*)p; p += (size_t)N * 32;
    short* ubN    = (short*)p; p += B * 16;
    short* ubA    = (short*)p; p += B * 32;
    short* ubB    = (short*)p; p += B * 32;
    short* WtAll  = (short*)p; p += 79872 / 2;
    const short* WtE0 = WtAll;
    const short* WtE1 = WtAll + 12288;
    const short* WtE2 = WtAll + 28672;
    const short* WtN0 = WtAll + 45056;
    const short* WtN1 = WtAll + 55296;
    const short* WtN2 = WtAll + 67584;

    // bf16 intermediate-e buffer (E x 64 shorts), if workspace has room
    short* eb16 = nullptr;
    {
        size_t used = (size_t)((char*)p - (char*)d_ws);
        used = (used + 15) & ~(size_t)15;
        size_t need = used + (size_t)E * 64 * sizeof(short);
        if (ws_size >= need) eb16 = (short*)((char*)d_ws + used);
    }

    const size_t EOFF = (size_t)N * 64;
    const size_t UOFF = EOFF + (size_t)E * 64;

    hipMemsetAsync(zbase, 0, zbytes, stream);

    detect_dtype<<<1, 256, 0, stream>>>((const unsigned short*)x_in, dflag);

    bn_stats<64><<<256, 256, 0, stream>>>(x_in, N, stats, dflag);
    bn_stats<32><<<512, 256, 0, stream>>>(e_raw, E, stats + 128, dflag);
    bn_stats<32><<<8,   256, 0, stream>>>(u_raw, B, stats + 256, dflag);
    bn_apply_x<<<512, 256, 0, stream>>>(x_in, xb0, stats, N, g_node, b_node, dflag);
    bn_apply_u<<<8,   256, 0, stream>>>(u_raw, uN, ubN, stats + 256, B, g_glob, b_glob, dflag);
    count_kernel<<<512, 256, 0, stream>>>(ei, cnt, E);
    csr_offsets<<<(N + 255) / 256, 256, 0, stream>>>(cnt, off, wcur, cursor, N, batchv, gstart, B);
    csr_fill<<<512, 256, 0, stream>>>(ei, wcur, csr, E);
    perm_build<<<512, 256, 0, stream>>>(ei, csr, sp, dp, E);
    transpose_w<<<48, 256, 0, stream>>>(We[0], We[1], We[2], Wn[0], Wn[1], Wn[2], WtAll, dflag);

    const int NG = (N + 63) / 64;   // 469
    const int NT = (E + 63) / 64;   // 4688 tiles
    const int EG0 = NT < 1280 ? NT : 1280;   // L0: 32KB LDS -> 5 blocks/CU
    const int EG  = NT < 1024 ? NT : 1024;   // L1/2: 40KB LDS -> 4 blocks/CU

    if (eb16) {
        // ---- bf16 intermediate-e flow, CSR-position ordering ----
        // layer 0: gather raw e via csr, write position-ordered bf16
        edge_mfma<true><<<EG0, 256, 0, stream>>>(
            sp, dp, csr, batchv, xb0, e_raw, 0, stats + 128, g_edge, b_edge,
            ubN, WtE0, be[0], eb16, 0, E, dflag, 0, 1, 0, nullptr);
        node_fused<true, false><<<NG, 256, 0, stream>>>(
            batchv, xb0, off, csr, cnt, eb16, 0, ubN, WtN0, bn[0], xb1, nullptr, N, dflag, 1, 1);
        pool_kernel<<<B * 8, 256, 0, stream>>>(gstart, xb1, gsum0);
        glob_gemm<32><<<B / 4, 256, 0, stream>>>(gstart, gsum0, uN, Wg[0], bg[0], uA, ubA, dflag);

        // layer 1 (position in / position out, in-place: wave-private row windows, safe)
        edge_mfma<false><<<EG, 256, 0, stream>>>(
            sp, dp, csr, batchv, xb1, eb16, 0, nullptr, nullptr, nullptr,
            ubA, WtE1, be[1], eb16, 0, E, dflag, 1, 1, 0, nullptr);
        node_fused<false, false><<<NG, 256, 0, stream>>>(
            batchv, xb1, off, csr, cnt, eb16, 0, ubA, WtN1, bn[1], xb0, nullptr, N, dflag, 1, 1);
        pool_kernel<<<B * 8, 256, 0, stream>>>(gstart, xb0, gsum1);
        glob_gemm<64><<<B / 4, 256, 0, stream>>>(gstart, gsum1, uA, Wg[1], bg[1], uB, ubB, dflag);

        // layer 2: final e -> d_out scattered to ORIGINAL edge order + bf16 position copy for node gather
        edge_mfma<false><<<EG, 256, 0, stream>>>(
            sp, dp, csr, batchv, xb0, eb16, 0, nullptr, nullptr, nullptr,
            ubB, WtE2, be[2], d_out, EOFF, E, dflag, 1, 0, 1, eb16);
        node_fused<false, true><<<NG, 256, 0, stream>>>(
            batchv, xb0, off, csr, cnt, eb16, 0, ubB, WtN2, bn[2], xb1, d_out, N, dflag, 1, 1);
        pool_kernel<<<B * 8, 256, 0, stream>>>(gstart, xb1, gsum2);
        glob_gemm<64><<<B / 4, 256, 0, stream>>>(gstart, gsum2, uB, Wg[2], bg[2], uA, ubA, dflag);
    } else {
        // ---- fallback: original edge-id ordering, e intermediate in d_out (input dtype) ----
        edge_mfma<true><<<EG0, 256, 0, stream>>>(
            ei, ei + E, nullptr, batchv, xb0, e_raw, 0, stats + 128, g_edge, b_edge,
            ubN, WtE0, be[0], d_out, EOFF, E, dflag, 0, 0, 0, nullptr);
        node_fused<true, false><<<NG, 256, 0, stream>>>(
            batchv, xb0, off, csr, cnt, d_out, EOFF, ubN, WtN0, bn[0], xb1, nullptr, N, dflag, 0, 0);
        pool_kernel<<<B * 8, 256, 0, stream>>>(gstart, xb1, gsum0);
        glob_gemm<32><<<B / 4, 256, 0, stream>>>(gstart, gsum0, uN, Wg[0], bg[0], uA, ubA, dflag);

        edge_mfma<false><<<EG, 256, 0, stream>>>(
            ei, ei + E, nullptr, batchv, xb1, d_out, EOFF, nullptr, nullptr, nullptr,
            ubA, WtE1, be[1], d_out, EOFF, E, dflag, 0, 0, 0, nullptr);
        node_fused<false, false><<<NG, 256, 0, stream>>>(
            batchv, xb1, off, csr, cnt, d_out, EOFF, ubA, WtN1, bn[1], xb0, nullptr, N, dflag, 0, 0);
        pool_kernel<<<B * 8, 256, 0, stream>>>(gstart, xb0, gsum1);
        glob_gemm<64><<<B / 4, 256, 0, stream>>>(gstart, gsum1, uA, Wg[1], bg[1], uB, ubB, dflag);

        edge_mfma<false><<<EG, 256, 0, stream>>>(
            ei, ei + E, nullptr, batchv, xb0, d_out, EOFF, nullptr, nullptr, nullptr,
            ubB, WtE2, be[2], d_out, EOFF, E, dflag, 0, 0, 0, nullptr);
        node_fused<false, true><<<NG, 256, 0, stream>>>(
            batchv, xb0, off, csr, cnt, d_out, EOFF, ubB, WtN2, bn[2], xb1, d_out, N, dflag, 0, 0);
        pool_kernel<<<B * 8, 256, 0, stream>>>(gstart, xb1, gsum2);
        glob_gemm<64><<<B / 4, 256, 0, stream>>>(gstart, gsum2, uB, Wg[2], bg[2], uA, ubA, dflag);
    }

    // ---- u output ----
    cast_out<<<16, 256, 0, stream>>>(uA, d_out, UOFF, B * 64, dflag);
}